// Round 1
// baseline (4739.393 us; speedup 1.0000x reference)
//
#include <hip/hip_runtime.h>

// Problem constants (fixed by the reference)
#define N_ROWS 262144
#define D 80           // input feature dim
#define DA 81          // augmented dim [x, 1]
#define MSTRIDE 84     // column stride for bilinear matrices
#define DOUT 160
#define EPS 1e-5f

// ws layout (in floats)
#define S_OFF   0                      // 3 x (81*81) second-moment matrices
#define S_SIZE  (DA * DA)              // 6561
#define T_OFF   (3 * S_SIZE)           // T = W~ @ S~  (3 x 160x81)
#define T_SIZE  (DOUT * DA)
#define WP_OFF  (T_OFF + 3 * T_SIZE)   // W' effective weights (3 x 160x81)
#define WP_SIZE (DOUT * DA)
// 16B-aligned so k3 can float4-load M columns (MSTRIDE=84 -> 21 float4/col)
#define MC_OFF  ((WP_OFF + 3 * WP_SIZE + 3) & ~3) // Mc[q][k*84+i] = M_q[i,k]
#define MC_SIZE (DA * MSTRIDE)

// ---------------------------------------------------------------------------
// K1: per-input augmented second moments S~ = sum_rows [x,1][x,1]^T
//     8x8 per-lane tiles over the UPPER TRIANGLE (55 pairs per wave),
//     float4 LDS reads, block-level LDS reduction, mirrored atomics.
// ---------------------------------------------------------------------------
__global__ __launch_bounds__(256) void k1_moments(const float* __restrict__ xs,
                                                  const float* __restrict__ xl,
                                                  const float* __restrict__ xr,
                                                  float* __restrict__ ws) {
    const float* x = (blockIdx.y == 0) ? xs : (blockIdx.y == 1) ? xl : xr;
    float* S = ws + S_OFF + blockIdx.y * S_SIZE;

    __shared__ float lds[3600];  // tile: 32x80 = 2560 floats; reduce: 3520+80

    const int tid = threadIdx.x;
    const int wave = tid >> 6;
    const int lane = tid & 63;

    // lane -> upper-triangle pair (ti<=tj) of the 10x10 8-chunk grid
    int ti = -1, tj = -1;
    if (lane < 55) {
        int l = lane, a = 0;
        while (l >= 10 - a) { l -= 10 - a; a++; }
        ti = a; tj = a + l;
    }

    float acc[8][8];
#pragma unroll
    for (int u = 0; u < 8; u++)
#pragma unroll
        for (int v = 0; v < 8; v++) acc[u][v] = 0.f;
    float csum[8];
#pragma unroll
    for (int u = 0; u < 8; u++) csum[u] = 0.f;

    const int rowsPerBlock = N_ROWS / 256;  // gridDim.x == 256 -> 1024
    const size_t base = (size_t)blockIdx.x * rowsPerBlock * D;

    for (int t0 = 0; t0 < rowsPerBlock; t0 += 32) {
        __syncthreads();
        // stage 32 rows (2560 floats = 640 float4), fully coalesced
        const float4* src = reinterpret_cast<const float4*>(x + base + (size_t)t0 * D);
        float4* dst4 = reinterpret_cast<float4*>(lds);
        for (int idx = tid; idx < 640; idx += 256) dst4[idx] = src[idx];
        __syncthreads();

        if (ti >= 0) {
            const int rbase = wave * 8;  // each wave owns 8 of the 32 rows
#pragma unroll 2
            for (int rr = 0; rr < 8; rr++) {
                const float* row = &lds[(rbase + rr) * D];
                float a8[8], b8[8];
                *reinterpret_cast<float4*>(&a8[0]) = *reinterpret_cast<const float4*>(&row[ti * 8]);
                *reinterpret_cast<float4*>(&a8[4]) = *reinterpret_cast<const float4*>(&row[ti * 8 + 4]);
                *reinterpret_cast<float4*>(&b8[0]) = *reinterpret_cast<const float4*>(&row[tj * 8]);
                *reinterpret_cast<float4*>(&b8[4]) = *reinterpret_cast<const float4*>(&row[tj * 8 + 4]);
#pragma unroll
                for (int u = 0; u < 8; u++)
#pragma unroll
                    for (int v = 0; v < 8; v++) acc[u][v] += a8[u] * b8[v];
                if (ti == tj) {
#pragma unroll
                    for (int u = 0; u < 8; u++) csum[u] += a8[u];
                }
            }
        }
    }

    // block-level reduce across the 4 waves (serialized rounds, LDS RMW)
    __syncthreads();
    for (int i = tid; i < 3600; i += 256) lds[i] = 0.f;
    __syncthreads();
    for (int w = 0; w < 4; w++) {
        if (wave == w && ti >= 0) {
            float* dst = &lds[lane * 64];
#pragma unroll
            for (int u = 0; u < 8; u++)
#pragma unroll
                for (int v = 0; v < 8; v++) dst[u * 8 + v] += acc[u][v];
            if (ti == tj) {
#pragma unroll
                for (int u = 0; u < 8; u++) lds[3520 + ti * 8 + u] += csum[u];
            }
        }
        __syncthreads();
    }

    // global atomics (upper triangle + mirror)
    for (int e = tid; e < 3520; e += 256) {
        int p = e >> 6, o = e & 63;
        int l = p, a = 0;
        while (l >= 10 - a) { l -= 10 - a; a++; }
        const int pi = a, pj = a + l;
        const int i = pi * 8 + (o >> 3), j = pj * 8 + (o & 7);
        const float v = lds[e];
        atomicAdd(&S[i * DA + j], v);
        if (pi != pj) atomicAdd(&S[j * DA + i], v);
    }
    for (int c = tid; c < D; c += 256) {
        const float v = lds[3520 + c];
        atomicAdd(&S[c * DA + D], v);  // column 80
        atomicAdd(&S[D * DA + c], v);  // row 80
    }
    // corner S[80,80] = N handled inline in k2_T
}

// ---------------------------------------------------------------------------
// K2a: T[p][j][i] = sum_k W~[j,k] * S~[k,i]   (W~ = [W | b])
// ---------------------------------------------------------------------------
__global__ void k2_T(const float* __restrict__ Ws, const float* __restrict__ bs,
                     const float* __restrict__ Wl, const float* __restrict__ bl,
                     const float* __restrict__ Wr, const float* __restrict__ br,
                     float* __restrict__ ws) {
    int e = blockIdx.x * 256 + threadIdx.x;
    if (e >= 3 * DOUT * DA) return;
    int p = e / (DOUT * DA);
    int rem = e - p * (DOUT * DA);
    int j = rem / DA, i = rem - j * DA;

    const float* W = (p == 0) ? Ws : (p == 1) ? Wl : Wr;
    const float* b = (p == 0) ? bs : (p == 1) ? bl : br;
    const float* S = ws + S_OFF + p * S_SIZE;

    float a0 = 0.f, a1 = 0.f;
    for (int k = 0; k < D; k += 2) {
        a0 += W[j * D + k] * S[k * DA + i];
        a1 += W[j * D + k + 1] * S[(k + 1) * DA + i];
    }
    float s80 = (i == D) ? (float)N_ROWS : S[D * DA + i];
    ws[T_OFF + p * T_SIZE + j * DA + i] = a0 + a1 + b[j] * s80;
}

// ---------------------------------------------------------------------------
// K2b: per feature j: mu, var, a -> effective W'[j,:] (augmented)
// ---------------------------------------------------------------------------
__global__ void k2_scale(const float* __restrict__ Ws, const float* __restrict__ bs,
                         const float* __restrict__ gs, const float* __restrict__ bes,
                         const float* __restrict__ Wl, const float* __restrict__ bl,
                         const float* __restrict__ gl, const float* __restrict__ bel,
                         const float* __restrict__ Wr, const float* __restrict__ br,
                         const float* __restrict__ gr, const float* __restrict__ ber,
                         float* __restrict__ ws) {
    int e = blockIdx.x * 256 + threadIdx.x;
    if (e >= 3 * DOUT) return;
    int p = e / DOUT, j = e - p * DOUT;

    const float* W  = (p == 0) ? Ws  : (p == 1) ? Wl  : Wr;
    const float* b  = (p == 0) ? bs  : (p == 1) ? bl  : br;
    const float* g  = (p == 0) ? gs  : (p == 1) ? gl  : gr;
    const float* be = (p == 0) ? bes : (p == 1) ? bel : ber;

    const float* T = ws + T_OFF + p * T_SIZE + j * DA;
    float eh2 = 0.f;
    for (int k = 0; k < D; k++) eh2 += T[k] * W[j * D + k];
    eh2 += T[D] * b[j];
    const float invN = 1.0f / (float)N_ROWS;
    eh2 *= invN;
    float mu = T[D] * invN;
    float var = eh2 - mu * mu;
    float a = g[j] * rsqrtf(var + EPS);

    float* Wp = ws + WP_OFF + p * WP_SIZE + j * DA;
    for (int k = 0; k < D; k++) Wp[k] = a * W[j * D + k];
    Wp[D] = a * b[j] + be[j] - a * mu;
}

// ---------------------------------------------------------------------------
// K2c: bilinear matrices Mc[q][k*84+i] = sum_j W'_a[j,i] * W'_b[j,k]
//      q=0:(sub,left) q=1:(sub,right) q=2:(left,right)  (a = i-side/regs,
//      b = k-side/LDS in k3)
// ---------------------------------------------------------------------------
__global__ void k2_M(float* __restrict__ ws) {
    int e = blockIdx.x * 256 + threadIdx.x;
    if (e >= 3 * DA * DA) return;
    int q = e / (DA * DA);
    int rem = e - q * (DA * DA);
    int k = rem / DA, i = rem - k * DA;

    int pa = (q == 2) ? 1 : 0;  // i-side: sub, sub, left
    int pb = (q == 0) ? 1 : 2;  // k-side: left, right, right
    const float* Wa = ws + WP_OFF + pa * WP_SIZE;
    const float* Wb = ws + WP_OFF + pb * WP_SIZE;

    float a0 = 0.f, a1 = 0.f;
    for (int j = 0; j < DOUT; j += 2) {
        a0 += Wa[j * DA + i] * Wb[j * DA + k];
        a1 += Wa[(j + 1) * DA + i] * Wb[(j + 1) * DA + k];
    }
    ws[MC_OFF + q * MC_SIZE + k * MSTRIDE + i] = a0 + a1;
}

// ---------------------------------------------------------------------------
// K3: per row: 3 bilinear sims -> softmax -> combine.
//     i-side vector in regs (compile-time indexed, fully unrolled inner),
//     k-side = thread's OWN row in LDS (runtime-indexable private buffer).
//
//     M columns are fetched via the VECTOR path (global_load_dwordx4,
//     laundered zero offset in a VGPR): vmcnt-counted, deeply pipelined,
//     and DECOUPLED from the lgkmcnt-counted ds_read of the w-side.
//     (Scalar s_load of M shared lgkmcnt with ds_read -> every iteration
//     drained the whole column fetch; SGPR file was also exhausted.)
// ---------------------------------------------------------------------------
#define K3_ROWS 128
#define K3_F4   (K3_ROWS * D / 4)   // 2560 float4 per block chunk

__device__ __forceinline__ float bilin(const float* __restrict__ Mc,
                                       const float (&v)[D],
                                       const float* __restrict__ wlds,
                                       int lz) {
    const float4* __restrict__ M4 = reinterpret_cast<const float4*>(Mc);
    const float4* __restrict__ w4p = reinterpret_cast<const float4*>(wlds);
    float acc0 = 0.f, acc1 = 0.f;
#pragma unroll 2
    for (int k0 = 0; k0 < D / 4; k0++) {          // 20 iters, 4 columns each
        float4 w4 = w4p[k0];                       // one ds_read_b128 per 4 cols
        float d[4];
#pragma unroll
        for (int kk = 0; kk < 4; kk++) {
            // lz == 0 but lives in a VGPR -> divergent-looking address ->
            // global_load_dwordx4 (vmcnt), broadcast-coalesced across lanes
            const float4* __restrict__ col = M4 + (k0 * 4 + kk) * (MSTRIDE / 4) + lz;
            float s0 = 0.f, s1 = 0.f, s2 = 0.f, s3 = 0.f;
#pragma unroll
            for (int c = 0; c < D / 4; c++) {
                float4 m = col[c];
                s0 += m.x * v[c * 4 + 0];
                s1 += m.y * v[c * 4 + 1];
                s2 += m.z * v[c * 4 + 2];
                s3 += m.w * v[c * 4 + 3];
            }
            d[kk] = ((s0 + s1) + (s2 + s3)) + col[20].x;  // aug element i=80 (v=1)
        }
        acc0 += d[0] * w4.x + d[1] * w4.y;
        acc1 += d[2] * w4.z + d[3] * w4.w;
    }
    {   // k = 80 term (aug element of w = 1)
        const float4* __restrict__ col = M4 + D * (MSTRIDE / 4) + lz;
        float s0 = 0.f, s1 = 0.f, s2 = 0.f, s3 = 0.f;
#pragma unroll
        for (int c = 0; c < D / 4; c++) {
            float4 m = col[c];
            s0 += m.x * v[c * 4 + 0];
            s1 += m.y * v[c * 4 + 1];
            s2 += m.z * v[c * 4 + 2];
            s3 += m.w * v[c * 4 + 3];
        }
        acc0 += ((s0 + s1) + (s2 + s3)) + col[20].x;
    }
    return acc0 + acc1;
}

__global__ __launch_bounds__(K3_ROWS, 2) void k3_main(const float* __restrict__ xs_g,
                                                      const float* __restrict__ xl_g,
                                                      const float* __restrict__ xr_g,
                                                      const float* __restrict__ ws,
                                                      float* __restrict__ out) {
    __shared__ float lds[K3_ROWS * D];  // 40 KB -> 4 blocks/CU (8 waves)
    const int tid = threadIdx.x;
    const size_t blockBase = (size_t)blockIdx.x * K3_ROWS * D;
    float4* lds4 = reinterpret_cast<float4*>(lds);
    float* myrow = &lds[tid * D];
    const float4* myrow4 = reinterpret_cast<const float4*>(myrow);

    const float* Msl = ws + MC_OFF + 0 * MC_SIZE;
    const float* Msr = ws + MC_OFF + 1 * MC_SIZE;
    const float* Mlr = ws + MC_OFF + 2 * MC_SIZE;

    // laundered zero: forces M loads onto the vector-memory path
    int lz = 0;
    asm volatile("" : "+v"(lz));

    float v0[D], v1[D];  // xs, xl in registers (launch_bounds(128,2) -> no spill)

    // ---- stage xs -> LDS (coalesced), pull own row to regs ----
    {
        const float4* src = reinterpret_cast<const float4*>(xs_g + blockBase);
        for (int idx = tid; idx < K3_F4; idx += K3_ROWS) lds4[idx] = src[idx];
    }
    __syncthreads();
#pragma unroll
    for (int c = 0; c < D / 4; c++) {
        float4 t = myrow4[c];
        v0[c * 4] = t.x; v0[c * 4 + 1] = t.y; v0[c * 4 + 2] = t.z; v0[c * 4 + 3] = t.w;
    }
    __syncthreads();

    // ---- stage xl -> LDS, pull own row to regs, compute s0 ----
    {
        const float4* src = reinterpret_cast<const float4*>(xl_g + blockBase);
        for (int idx = tid; idx < K3_F4; idx += K3_ROWS) lds4[idx] = src[idx];
    }
    __syncthreads();
#pragma unroll
    for (int c = 0; c < D / 4; c++) {
        float4 t = myrow4[c];
        v1[c * 4] = t.x; v1[c * 4 + 1] = t.y; v1[c * 4 + 2] = t.z; v1[c * 4 + 3] = t.w;
    }
    float s0 = bilin(Msl, v0, myrow, lz);  // (sub regs, left lds)
    __syncthreads();

    // ---- stage xr -> LDS, compute s1, s2 ----
    {
        const float4* src = reinterpret_cast<const float4*>(xr_g + blockBase);
        for (int idx = tid; idx < K3_F4; idx += K3_ROWS) lds4[idx] = src[idx];
    }
    __syncthreads();
    float s1 = bilin(Msr, v0, myrow, lz);  // (sub regs, right lds)
    float s2 = bilin(Mlr, v1, myrow, lz);  // (left regs, right lds)

    // ---- softmax + combine (in-place into own LDS row), coalesced store ----
    float m = fmaxf(s0, fmaxf(s1, s2));
    float e0 = __expf(s0 - m), e1 = __expf(s1 - m), e2 = __expf(s2 - m);
    float inv = 1.0f / (e0 + e1 + e2);
    float p0 = e0 * inv, p1 = e1 * inv, p2 = e2 * inv;  // left, right, sub

    float4* myrow4w = reinterpret_cast<float4*>(myrow);
#pragma unroll
    for (int c = 0; c < D / 4; c++) {
        float4 r4 = myrow4[c];  // right
        float4 o;
        o.x = p0 * v1[c * 4 + 0] + p1 * r4.x + p2 * v0[c * 4 + 0];
        o.y = p0 * v1[c * 4 + 1] + p1 * r4.y + p2 * v0[c * 4 + 1];
        o.z = p0 * v1[c * 4 + 2] + p1 * r4.z + p2 * v0[c * 4 + 2];
        o.w = p0 * v1[c * 4 + 3] + p1 * r4.w + p2 * v0[c * 4 + 3];
        myrow4w[c] = o;  // own row: no barrier needed
    }
    __syncthreads();
    {
        float4* dst = reinterpret_cast<float4*>(out + blockBase);
        for (int idx = tid; idx < K3_F4; idx += K3_ROWS) dst[idx] = lds4[idx];
    }
}

// ---------------------------------------------------------------------------
extern "C" void kernel_launch(void* const* d_in, const int* in_sizes, int n_in,
                              void* d_out, int out_size, void* d_ws, size_t ws_size,
                              hipStream_t stream) {
    const float* xs = (const float*)d_in[0];
    const float* xl = (const float*)d_in[1];
    const float* xr = (const float*)d_in[2];
    const float* Wsub = (const float*)d_in[3];
    const float* bsub = (const float*)d_in[4];
    const float* gsub = (const float*)d_in[5];
    const float* besub = (const float*)d_in[6];
    const float* Wleft = (const float*)d_in[7];
    const float* bleft = (const float*)d_in[8];
    const float* gleft = (const float*)d_in[9];
    const float* beleft = (const float*)d_in[10];
    const float* Wright = (const float*)d_in[11];
    const float* bright = (const float*)d_in[12];
    const float* gright = (const float*)d_in[13];
    const float* beright = (const float*)d_in[14];
    float* ws = (float*)d_ws;
    float* out = (float*)d_out;

    hipMemsetAsync(ws + S_OFF, 0, 3 * S_SIZE * sizeof(float), stream);

    k1_moments<<<dim3(256, 3), 256, 0, stream>>>(xs, xl, xr, ws);
    k2_T<<<(3 * DOUT * DA + 255) / 256, 256, 0, stream>>>(
        Wsub, bsub, Wleft, bleft, Wright, bright, ws);
    k2_scale<<<(3 * DOUT + 255) / 256, 256, 0, stream>>>(
        Wsub, bsub, gsub, besub, Wleft, bleft, gleft, beleft,
        Wright, bright, gright, beright, ws);
    k2_M<<<(3 * DA * DA + 255) / 256, 256, 0, stream>>>(ws);
    k3_main<<<N_ROWS / K3_ROWS, K3_ROWS, 0, stream>>>(xs, xl, xr, ws, out);
}

// Round 2
// 4482.509 us; speedup vs baseline: 1.0573x; 1.0573x over previous
//
#include <hip/hip_runtime.h>

// Problem constants (fixed by the reference)
#define N_ROWS 262144
#define D 80           // input feature dim
#define DA 81          // augmented dim [x, 1]
#define MSTRIDE 84     // column stride for bilinear matrices
#define DOUT 160
#define EPS 1e-5f

// ws layout (in floats)
#define S_OFF   0                      // 3 x (81*81) second-moment matrices
#define S_SIZE  (DA * DA)              // 6561
#define T_OFF   (3 * S_SIZE)           // T = W~ @ S~  (3 x 160x81)
#define T_SIZE  (DOUT * DA)
#define WP_OFF  (T_OFF + 3 * T_SIZE)   // W' effective weights (3 x 160x81)
#define WP_SIZE (DOUT * DA)
// 16B-aligned so k3 can float4-load M columns (MSTRIDE=84 -> 21 float4/col)
#define MC_OFF  ((WP_OFF + 3 * WP_SIZE + 3) & ~3) // Mc[q][k*84+i] = W'_a[j,i]W'_b[j,k]
#define MC_SIZE (DA * MSTRIDE)

// ---------------------------------------------------------------------------
// K1: per-input augmented second moments S~ = sum_rows [x,1][x,1]^T
//     Double-buffered LDS staging (register prefetch: issue-early/write-late
//     so HBM latency hides under the 8x8 outer-product), 512 blocks/input.
// ---------------------------------------------------------------------------
#define K1_BLOCKS 512
#define K1_ROWS   (N_ROWS / K1_BLOCKS)   // 512 rows/block
#define K1_NT     (K1_ROWS / 32)         // 16 tiles of 32 rows

__global__ __launch_bounds__(256) void k1_moments(const float* __restrict__ xs,
                                                  const float* __restrict__ xl,
                                                  const float* __restrict__ xr,
                                                  float* __restrict__ ws) {
    const float* x = (blockIdx.y == 0) ? xs : (blockIdx.y == 1) ? xl : xr;
    float* S = ws + S_OFF + blockIdx.y * S_SIZE;

    // 2 staging buffers (32x80 = 2560 floats each) + 3600-float reduce area
    __shared__ float lds[2 * 2560 + 3600];   // 34.9 KB

    const int tid = threadIdx.x;
    const int wave = tid >> 6;
    const int lane = tid & 63;

    // lane -> upper-triangle pair (ti<=tj) of the 10x10 8-chunk grid
    int ti = -1, tj = -1;
    if (lane < 55) {
        int l = lane, a = 0;
        while (l >= 10 - a) { l -= 10 - a; a++; }
        ti = a; tj = a + l;
    }

    float acc[8][8];
#pragma unroll
    for (int u = 0; u < 8; u++)
#pragma unroll
        for (int v = 0; v < 8; v++) acc[u][v] = 0.f;
    float csum[8];
#pragma unroll
    for (int u = 0; u < 8; u++) csum[u] = 0.f;

    const size_t base = (size_t)blockIdx.x * K1_ROWS * D;
    const float4* __restrict__ gsrc = reinterpret_cast<const float4*>(x + base);

    // prologue: tile 0 -> buf0 (each tile = 640 float4 = 2*256 + 128)
    float4 r0, r1, r2;
    r0 = gsrc[tid]; r1 = gsrc[tid + 256]; if (tid < 128) r2 = gsrc[tid + 512];
    {
        float4* d4 = reinterpret_cast<float4*>(lds);
        d4[tid] = r0; d4[tid + 256] = r1; if (tid < 128) d4[tid + 512] = r2;
    }

    for (int t = 0; t < K1_NT; t++) {
        __syncthreads();   // buf[t&1] visible; all compute on buf[(t+1)&1] done
        if (t + 1 < K1_NT) {   // issue next tile's loads (vmcnt, no wait yet)
            const float4* __restrict__ s = gsrc + (size_t)(t + 1) * 640;
            r0 = s[tid]; r1 = s[tid + 256]; if (tid < 128) r2 = s[tid + 512];
        }
        const float* __restrict__ buf = lds + (t & 1) * 2560;
        if (ti >= 0) {
            const int rbase = wave * 8;  // each wave owns 8 of the 32 rows
#pragma unroll 2
            for (int rr = 0; rr < 8; rr++) {
                const float* row = &buf[(rbase + rr) * D];
                float a8[8], b8[8];
                *reinterpret_cast<float4*>(&a8[0]) = *reinterpret_cast<const float4*>(&row[ti * 8]);
                *reinterpret_cast<float4*>(&a8[4]) = *reinterpret_cast<const float4*>(&row[ti * 8 + 4]);
                *reinterpret_cast<float4*>(&b8[0]) = *reinterpret_cast<const float4*>(&row[tj * 8]);
                *reinterpret_cast<float4*>(&b8[4]) = *reinterpret_cast<const float4*>(&row[tj * 8 + 4]);
#pragma unroll
                for (int u = 0; u < 8; u++)
#pragma unroll
                    for (int v = 0; v < 8; v++) acc[u][v] += a8[u] * b8[v];
                if (ti == tj) {
#pragma unroll
                    for (int u = 0; u < 8; u++) csum[u] += a8[u];
                }
            }
        }
        if (t + 1 < K1_NT) {   // write prefetched tile (vmcnt drain here, after compute)
            float4* d4 = reinterpret_cast<float4*>(lds + ((t + 1) & 1) * 2560);
            d4[tid] = r0; d4[tid + 256] = r1; if (tid < 128) d4[tid + 512] = r2;
        }
    }

    // block-level reduce across the 4 waves (serialized rounds, LDS RMW)
    float* red = lds + 5120;
    __syncthreads();
    for (int i = tid; i < 3600; i += 256) red[i] = 0.f;
    __syncthreads();
    for (int w = 0; w < 4; w++) {
        if (wave == w && ti >= 0) {
            float* dst = &red[lane * 64];
#pragma unroll
            for (int u = 0; u < 8; u++)
#pragma unroll
                for (int v = 0; v < 8; v++) dst[u * 8 + v] += acc[u][v];
            if (ti == tj) {
#pragma unroll
                for (int u = 0; u < 8; u++) red[3520 + ti * 8 + u] += csum[u];
            }
        }
        __syncthreads();
    }

    // global atomics (upper triangle + mirror)
    for (int e = tid; e < 3520; e += 256) {
        int p = e >> 6, o = e & 63;
        int l = p, a = 0;
        while (l >= 10 - a) { l -= 10 - a; a++; }
        const int pi = a, pj = a + l;
        const int i = pi * 8 + (o >> 3), j = pj * 8 + (o & 7);
        const float v = red[e];
        atomicAdd(&S[i * DA + j], v);
        if (pi != pj) atomicAdd(&S[j * DA + i], v);
    }
    for (int c = tid; c < D; c += 256) {
        const float v = red[3520 + c];
        atomicAdd(&S[c * DA + D], v);  // column 80
        atomicAdd(&S[D * DA + c], v);  // row 80
    }
    // corner S[80,80] = N handled inline in k2_T
}

// ---------------------------------------------------------------------------
// K2a: T[p][j][i] = sum_k W~[j,k] * S~[k,i]   (W~ = [W | b])
// ---------------------------------------------------------------------------
__global__ void k2_T(const float* __restrict__ Ws, const float* __restrict__ bs,
                     const float* __restrict__ Wl, const float* __restrict__ bl,
                     const float* __restrict__ Wr, const float* __restrict__ br,
                     float* __restrict__ ws) {
    int e = blockIdx.x * 256 + threadIdx.x;
    if (e >= 3 * DOUT * DA) return;
    int p = e / (DOUT * DA);
    int rem = e - p * (DOUT * DA);
    int j = rem / DA, i = rem - j * DA;

    const float* W = (p == 0) ? Ws : (p == 1) ? Wl : Wr;
    const float* b = (p == 0) ? bs : (p == 1) ? bl : br;
    const float* S = ws + S_OFF + p * S_SIZE;

    float a0 = 0.f, a1 = 0.f;
    for (int k = 0; k < D; k += 2) {
        a0 += W[j * D + k] * S[k * DA + i];
        a1 += W[j * D + k + 1] * S[(k + 1) * DA + i];
    }
    float s80 = (i == D) ? (float)N_ROWS : S[D * DA + i];
    ws[T_OFF + p * T_SIZE + j * DA + i] = a0 + a1 + b[j] * s80;
}

// ---------------------------------------------------------------------------
// K2b: per feature j: mu, var, a -> effective W'[j,:] (augmented)
// ---------------------------------------------------------------------------
__global__ void k2_scale(const float* __restrict__ Ws, const float* __restrict__ bs,
                         const float* __restrict__ gs, const float* __restrict__ bes,
                         const float* __restrict__ Wl, const float* __restrict__ bl,
                         const float* __restrict__ gl, const float* __restrict__ bel,
                         const float* __restrict__ Wr, const float* __restrict__ br,
                         const float* __restrict__ gr, const float* __restrict__ ber,
                         float* __restrict__ ws) {
    int e = blockIdx.x * 256 + threadIdx.x;
    if (e >= 3 * DOUT) return;
    int p = e / DOUT, j = e - p * DOUT;

    const float* W  = (p == 0) ? Ws  : (p == 1) ? Wl  : Wr;
    const float* b  = (p == 0) ? bs  : (p == 1) ? bl  : br;
    const float* g  = (p == 0) ? gs  : (p == 1) ? gl  : gr;
    const float* be = (p == 0) ? bes : (p == 1) ? bel : ber;

    const float* T = ws + T_OFF + p * T_SIZE + j * DA;
    float eh2 = 0.f;
    for (int k = 0; k < D; k++) eh2 += T[k] * W[j * D + k];
    eh2 += T[D] * b[j];
    const float invN = 1.0f / (float)N_ROWS;
    eh2 *= invN;
    float mu = T[D] * invN;
    float var = eh2 - mu * mu;
    float a = g[j] * rsqrtf(var + EPS);

    float* Wp = ws + WP_OFF + p * WP_SIZE + j * DA;
    for (int k = 0; k < D; k++) Wp[k] = a * W[j * D + k];
    Wp[D] = a * b[j] + be[j] - a * mu;
}

// ---------------------------------------------------------------------------
// K2c: bilinear matrices Mc[q][k*84+i] = sum_j W'_a[j,i] * W'_b[j,k]
//      a = i-side (k3 register vector), b = k-side (k3 LDS own-row).
//      q=0: (a=sub,  b=left )  -> s0 computed with v=sub,   w=left
//      q=1: (a=right,b=sub  )  -> s1 computed with v=right, w=sub   (transposed!)
//      q=2: (a=left, b=right)  -> s2 computed with v=left,  w=right
// ---------------------------------------------------------------------------
__global__ void k2_M(float* __restrict__ ws) {
    int e = blockIdx.x * 256 + threadIdx.x;
    if (e >= 3 * DA * DA) return;
    int q = e / (DA * DA);
    int rem = e - q * (DA * DA);
    int k = rem / DA, i = rem - k * DA;

    int pa = (q == 1) ? 2 : (q == 2) ? 1 : 0;  // i-side: sub, right, left
    int pb = (q == 1) ? 0 : (q == 0) ? 1 : 2;  // k-side: left, sub,  right
    const float* Wa = ws + WP_OFF + pa * WP_SIZE;
    const float* Wb = ws + WP_OFF + pb * WP_SIZE;

    float a0 = 0.f, a1 = 0.f;
    for (int j = 0; j < DOUT; j += 2) {
        a0 += Wa[j * DA + i] * Wb[j * DA + k];
        a1 += Wa[(j + 1) * DA + i] * Wb[(j + 1) * DA + k];
    }
    ws[MC_OFF + q * MC_SIZE + k * MSTRIDE + i] = a0 + a1;
}

// ---------------------------------------------------------------------------
// K3: per row: 3 bilinear sims -> softmax -> combine.
//     ONE 80-float register vector at a time (the round-1 spill disaster came
//     from holding two).  Sims are ordered so each step's register vector is
//     pulled from the tile staged in the previous step:
//       stage L -> v=L -> stage R -> s2=(L,R) -> v=R -> stage S -> s1=(R,S)
//       -> v=S -> stage L -> s0=(S,L) -> fold p2*S+p0*L into v -> stage R
//       -> out = v + p1*R.
//     M columns go through the VECTOR path (laundered VGPR offset ->
//     global_load_dwordx4): vmcnt-counted, ~27 KB/matrix L1/L2-resident,
//     broadcast-coalesced, decoupled from the lgkmcnt ds_read of w.
// ---------------------------------------------------------------------------
#define K3_ROWS 128
#define K3_F4   (K3_ROWS * D / 4)   // 2560 float4 per block tile

__device__ __forceinline__ void k3_stage(const float* __restrict__ g, size_t blockBase,
                                         float4* __restrict__ lds4, int tid) {
    const float4* __restrict__ src = reinterpret_cast<const float4*>(g + blockBase);
#pragma unroll
    for (int it = 0; it < K3_F4 / K3_ROWS; it++)
        lds4[tid + it * K3_ROWS] = src[tid + it * K3_ROWS];
}

__device__ __forceinline__ void k3_pull(float (&v)[D], const float4* __restrict__ myrow4) {
#pragma unroll
    for (int c = 0; c < D / 4; c++) {
        float4 t = myrow4[c];
        v[c * 4 + 0] = t.x; v[c * 4 + 1] = t.y;
        v[c * 4 + 2] = t.z; v[c * 4 + 3] = t.w;
    }
}

__device__ __forceinline__ float bilin(const float* __restrict__ Mc,
                                       const float (&v)[D],
                                       const float* __restrict__ wlds,
                                       int lz) {
    const float4* __restrict__ M4 = reinterpret_cast<const float4*>(Mc) + lz;
    const float4* __restrict__ w4p = reinterpret_cast<const float4*>(wlds);
    float acc0 = 0.f, acc1 = 0.f;
#pragma unroll 2
    for (int k0 = 0; k0 < D / 4; k0++) {          // 20 iters, 4 columns each
        float4 w4 = w4p[k0];                       // ds_read_b128 (lgkmcnt only)
        float d[4];
#pragma unroll
        for (int kk = 0; kk < 4; kk++) {
            const float4* __restrict__ col = M4 + (k0 * 4 + kk) * (MSTRIDE / 4);
            float s0 = 0.f, s1 = 0.f, s2 = 0.f, s3 = 0.f;
#pragma unroll
            for (int c = 0; c < D / 4; c++) {
                float4 m = col[c];                 // global_load_dwordx4 (vmcnt)
                s0 += m.x * v[c * 4 + 0];
                s1 += m.y * v[c * 4 + 1];
                s2 += m.z * v[c * 4 + 2];
                s3 += m.w * v[c * 4 + 3];
            }
            d[kk] = ((s0 + s1) + (s2 + s3)) + col[20].x;  // aug i=80 (v~=1)
        }
        acc0 += d[0] * w4.x + d[1] * w4.y;
        acc1 += d[2] * w4.z + d[3] * w4.w;
    }
    {   // k = 80 term (aug element of w~ = 1)
        const float4* __restrict__ col = M4 + D * (MSTRIDE / 4);
        float s0 = 0.f, s1 = 0.f, s2 = 0.f, s3 = 0.f;
#pragma unroll
        for (int c = 0; c < D / 4; c++) {
            float4 m = col[c];
            s0 += m.x * v[c * 4 + 0];
            s1 += m.y * v[c * 4 + 1];
            s2 += m.z * v[c * 4 + 2];
            s3 += m.w * v[c * 4 + 3];
        }
        acc0 += ((s0 + s1) + (s2 + s3)) + col[20].x;
    }
    return acc0 + acc1;
}

__global__ __launch_bounds__(K3_ROWS, 2) void k3_main(const float* __restrict__ xs_g,
                                                      const float* __restrict__ xl_g,
                                                      const float* __restrict__ xr_g,
                                                      const float* __restrict__ ws,
                                                      float* __restrict__ out) {
    __shared__ float lds[K3_ROWS * D];  // 40 KB -> 4 blocks/CU (8 waves)
    const int tid = threadIdx.x;
    const size_t blockBase = (size_t)blockIdx.x * K3_ROWS * D;
    float4* lds4 = reinterpret_cast<float4*>(lds);
    float* myrow = &lds[tid * D];
    const float4* myrow4 = reinterpret_cast<const float4*>(myrow);
    float4* myrow4w = reinterpret_cast<float4*>(myrow);

    const float* Msl = ws + MC_OFF + 0 * MC_SIZE;
    const float* Msr = ws + MC_OFF + 1 * MC_SIZE;   // stored transposed (a=right)
    const float* Mlr = ws + MC_OFF + 2 * MC_SIZE;

    // laundered zero: forces M loads onto the vector-memory path
    int lz = 0;
    asm volatile("" : "+v"(lz));

    float v[D];  // the ONE register vector

    // ---- stage LEFT, pull v=left ----
    k3_stage(xl_g, blockBase, lds4, tid);
    __syncthreads();
    k3_pull(v, myrow4);                 // v = left
    __syncthreads();

    // ---- stage RIGHT, s2 = (left regs, right lds), then v=right ----
    k3_stage(xr_g, blockBase, lds4, tid);
    __syncthreads();
    float s2 = bilin(Mlr, v, myrow, lz);
    k3_pull(v, myrow4);                 // v = right
    __syncthreads();

    // ---- stage SUB, s1 = (right regs, sub lds), then v=sub ----
    k3_stage(xs_g, blockBase, lds4, tid);
    __syncthreads();
    float s1 = bilin(Msr, v, myrow, lz);
    k3_pull(v, myrow4);                 // v = sub
    __syncthreads();

    // ---- stage LEFT again, s0 = (sub regs, left lds) ----
    k3_stage(xl_g, blockBase, lds4, tid);
    __syncthreads();
    float s0 = bilin(Msl, v, myrow, lz);

    // ---- softmax ----
    float m = fmaxf(s0, fmaxf(s1, s2));
    float e0 = __expf(s0 - m), e1 = __expf(s1 - m), e2 = __expf(s2 - m);
    float inv = 1.0f / (e0 + e1 + e2);
    float p0 = e0 * inv, p1 = e1 * inv, p2 = e2 * inv;  // left, right, sub

    // ---- fold p2*sub + p0*left into v (left is in LDS) ----
#pragma unroll
    for (int c = 0; c < D / 4; c++) {
        float4 L = myrow4[c];
        v[c * 4 + 0] = p2 * v[c * 4 + 0] + p0 * L.x;
        v[c * 4 + 1] = p2 * v[c * 4 + 1] + p0 * L.y;
        v[c * 4 + 2] = p2 * v[c * 4 + 2] + p0 * L.z;
        v[c * 4 + 3] = p2 * v[c * 4 + 3] + p0 * L.w;
    }
    __syncthreads();

    // ---- stage RIGHT again, finish combine into own LDS row, store ----
    k3_stage(xr_g, blockBase, lds4, tid);
    __syncthreads();
#pragma unroll
    for (int c = 0; c < D / 4; c++) {
        float4 R = myrow4[c];
        float4 o;
        o.x = v[c * 4 + 0] + p1 * R.x;
        o.y = v[c * 4 + 1] + p1 * R.y;
        o.z = v[c * 4 + 2] + p1 * R.z;
        o.w = v[c * 4 + 3] + p1 * R.w;
        myrow4w[c] = o;  // own row only: safe
    }
    __syncthreads();
    {
        float4* dst = reinterpret_cast<float4*>(out + blockBase);
#pragma unroll
        for (int it = 0; it < K3_F4 / K3_ROWS; it++)
            dst[tid + it * K3_ROWS] = lds4[tid + it * K3_ROWS];
    }
}

// ---------------------------------------------------------------------------
extern "C" void kernel_launch(void* const* d_in, const int* in_sizes, int n_in,
                              void* d_out, int out_size, void* d_ws, size_t ws_size,
                              hipStream_t stream) {
    const float* xs = (const float*)d_in[0];
    const float* xl = (const float*)d_in[1];
    const float* xr = (const float*)d_in[2];
    const float* Wsub = (const float*)d_in[3];
    const float* bsub = (const float*)d_in[4];
    const float* gsub = (const float*)d_in[5];
    const float* besub = (const float*)d_in[6];
    const float* Wleft = (const float*)d_in[7];
    const float* bleft = (const float*)d_in[8];
    const float* gleft = (const float*)d_in[9];
    const float* beleft = (const float*)d_in[10];
    const float* Wright = (const float*)d_in[11];
    const float* bright = (const float*)d_in[12];
    const float* gright = (const float*)d_in[13];
    const float* beright = (const float*)d_in[14];
    float* ws = (float*)d_ws;
    float* out = (float*)d_out;

    hipMemsetAsync(ws + S_OFF, 0, 3 * S_SIZE * sizeof(float), stream);

    k1_moments<<<dim3(K1_BLOCKS, 3), 256, 0, stream>>>(xs, xl, xr, ws);
    k2_T<<<(3 * DOUT * DA + 255) / 256, 256, 0, stream>>>(
        Wsub, bsub, Wleft, bleft, Wright, bright, ws);
    k2_scale<<<(3 * DOUT + 255) / 256, 256, 0, stream>>>(
        Wsub, bsub, gsub, besub, Wleft, bleft, gleft, beleft,
        Wright, bright, gright, beright, ws);
    k2_M<<<(3 * DA * DA + 255) / 256, 256, 0, stream>>>(ws);
    k3_main<<<N_ROWS / K3_ROWS, K3_ROWS, 0, stream>>>(xs, xl, xr, ws, out);
}

// Round 4
// 2239.376 us; speedup vs baseline: 2.1164x; 2.0017x over previous
//
#include <hip/hip_runtime.h>

// Problem constants (fixed by the reference)
#define N_ROWS 262144
#define D 80           // input feature dim
#define DA 81          // augmented dim [x, 1]
#define MSTRIDE 84     // column stride for bilinear matrices
#define DOUT 160
#define EPS 1e-5f

// ws layout (in floats)
#define S_OFF   0                      // 3 x (81*81) second-moment matrices
#define S_SIZE  (DA * DA)              // 6561
#define T_OFF   (3 * S_SIZE)           // T = W~ @ S~  (3 x 160x81)
#define T_SIZE  (DOUT * DA)
#define WP_OFF  (T_OFF + 3 * T_SIZE)   // W' effective weights (3 x 160x81)
#define WP_SIZE (DOUT * DA)
#define MC_OFF  ((WP_OFF + 3 * WP_SIZE + 3) & ~3) // Mc[q][k*84+i] = W'_a[j,i]W'_b[j,k]
#define MC_SIZE (DA * MSTRIDE)

// ---------------------------------------------------------------------------
// K1: per-input augmented second moments S~ = sum_rows [x,1][x,1]^T
//     Double-buffered LDS staging (register prefetch: issue-early/write-late
//     so HBM latency hides under the 8x8 outer-product), 512 blocks/input.
// ---------------------------------------------------------------------------
#define K1_BLOCKS 512
#define K1_ROWS   (N_ROWS / K1_BLOCKS)   // 512 rows/block
#define K1_NT     (K1_ROWS / 32)         // 16 tiles of 32 rows

__global__ __launch_bounds__(256) void k1_moments(const float* __restrict__ xs,
                                                  const float* __restrict__ xl,
                                                  const float* __restrict__ xr,
                                                  float* __restrict__ ws) {
    const float* x = (blockIdx.y == 0) ? xs : (blockIdx.y == 1) ? xl : xr;
    float* S = ws + S_OFF + blockIdx.y * S_SIZE;

    // 2 staging buffers (32x80 = 2560 floats each) + 3600-float reduce area
    __shared__ float lds[2 * 2560 + 3600];   // 34.9 KB

    const int tid = threadIdx.x;
    const int wave = tid >> 6;
    const int lane = tid & 63;

    // lane -> upper-triangle pair (ti<=tj) of the 10x10 8-chunk grid
    int ti = -1, tj = -1;
    if (lane < 55) {
        int l = lane, a = 0;
        while (l >= 10 - a) { l -= 10 - a; a++; }
        ti = a; tj = a + l;
    }

    float acc[8][8];
#pragma unroll
    for (int u = 0; u < 8; u++)
#pragma unroll
        for (int v = 0; v < 8; v++) acc[u][v] = 0.f;
    float csum[8];
#pragma unroll
    for (int u = 0; u < 8; u++) csum[u] = 0.f;

    const size_t base = (size_t)blockIdx.x * K1_ROWS * D;
    const float4* __restrict__ gsrc = reinterpret_cast<const float4*>(x + base);

    // prologue: tile 0 -> buf0 (each tile = 640 float4 = 2*256 + 128)
    float4 r0, r1, r2;
    r0 = gsrc[tid]; r1 = gsrc[tid + 256]; if (tid < 128) r2 = gsrc[tid + 512];
    {
        float4* d4 = reinterpret_cast<float4*>(lds);
        d4[tid] = r0; d4[tid + 256] = r1; if (tid < 128) d4[tid + 512] = r2;
    }

    for (int t = 0; t < K1_NT; t++) {
        __syncthreads();   // buf[t&1] visible; all compute on buf[(t+1)&1] done
        if (t + 1 < K1_NT) {   // issue next tile's loads (vmcnt, no wait yet)
            const float4* __restrict__ s = gsrc + (size_t)(t + 1) * 640;
            r0 = s[tid]; r1 = s[tid + 256]; if (tid < 128) r2 = s[tid + 512];
        }
        const float* __restrict__ buf = lds + (t & 1) * 2560;
        if (ti >= 0) {
            const int rbase = wave * 8;  // each wave owns 8 of the 32 rows
#pragma unroll 2
            for (int rr = 0; rr < 8; rr++) {
                const float* row = &buf[(rbase + rr) * D];
                float a8[8], b8[8];
                *reinterpret_cast<float4*>(&a8[0]) = *reinterpret_cast<const float4*>(&row[ti * 8]);
                *reinterpret_cast<float4*>(&a8[4]) = *reinterpret_cast<const float4*>(&row[ti * 8 + 4]);
                *reinterpret_cast<float4*>(&b8[0]) = *reinterpret_cast<const float4*>(&row[tj * 8]);
                *reinterpret_cast<float4*>(&b8[4]) = *reinterpret_cast<const float4*>(&row[tj * 8 + 4]);
#pragma unroll
                for (int u = 0; u < 8; u++)
#pragma unroll
                    for (int v = 0; v < 8; v++) acc[u][v] += a8[u] * b8[v];
                if (ti == tj) {
#pragma unroll
                    for (int u = 0; u < 8; u++) csum[u] += a8[u];
                }
            }
        }
        if (t + 1 < K1_NT) {   // write prefetched tile (vmcnt drain here, after compute)
            float4* d4 = reinterpret_cast<float4*>(lds + ((t + 1) & 1) * 2560);
            d4[tid] = r0; d4[tid + 256] = r1; if (tid < 128) d4[tid + 512] = r2;
        }
    }

    // block-level reduce across the 4 waves (serialized rounds, LDS RMW)
    float* red = lds + 5120;
    __syncthreads();
    for (int i = tid; i < 3600; i += 256) red[i] = 0.f;
    __syncthreads();
    for (int w = 0; w < 4; w++) {
        if (wave == w && ti >= 0) {
            float* dst = &red[lane * 64];
#pragma unroll
            for (int u = 0; u < 8; u++)
#pragma unroll
                for (int v = 0; v < 8; v++) dst[u * 8 + v] += acc[u][v];
            if (ti == tj) {
#pragma unroll
                for (int u = 0; u < 8; u++) red[3520 + ti * 8 + u] += csum[u];
            }
        }
        __syncthreads();
    }

    // global atomics (upper triangle + mirror)
    for (int e = tid; e < 3520; e += 256) {
        int p = e >> 6, o = e & 63;
        int l = p, a = 0;
        while (l >= 10 - a) { l -= 10 - a; a++; }
        const int pi = a, pj = a + l;
        const int i = pi * 8 + (o >> 3), j = pj * 8 + (o & 7);
        const float v = red[e];
        atomicAdd(&S[i * DA + j], v);
        if (pi != pj) atomicAdd(&S[j * DA + i], v);
    }
    for (int c = tid; c < D; c += 256) {
        const float v = red[3520 + c];
        atomicAdd(&S[c * DA + D], v);  // column 80
        atomicAdd(&S[D * DA + c], v);  // row 80
    }
    // corner S[80,80] = N handled inline in k2_T
}

// ---------------------------------------------------------------------------
// K2a: T[p][j][i] = sum_k W~[j,k] * S~[k,i]   (W~ = [W | b])
// ---------------------------------------------------------------------------
__global__ void k2_T(const float* __restrict__ Ws, const float* __restrict__ bs,
                     const float* __restrict__ Wl, const float* __restrict__ bl,
                     const float* __restrict__ Wr, const float* __restrict__ br,
                     float* __restrict__ ws) {
    int e = blockIdx.x * 256 + threadIdx.x;
    if (e >= 3 * DOUT * DA) return;
    int p = e / (DOUT * DA);
    int rem = e - p * (DOUT * DA);
    int j = rem / DA, i = rem - j * DA;

    const float* W = (p == 0) ? Ws : (p == 1) ? Wl : Wr;
    const float* b = (p == 0) ? bs : (p == 1) ? bl : br;
    const float* S = ws + S_OFF + p * S_SIZE;

    float a0 = 0.f, a1 = 0.f;
    for (int k = 0; k < D; k += 2) {
        a0 += W[j * D + k] * S[k * DA + i];
        a1 += W[j * D + k + 1] * S[(k + 1) * DA + i];
    }
    float s80 = (i == D) ? (float)N_ROWS : S[D * DA + i];
    ws[T_OFF + p * T_SIZE + j * DA + i] = a0 + a1 + b[j] * s80;
}

// ---------------------------------------------------------------------------
// K2b: per feature j: mu, var, a -> effective W'[j,:] (augmented)
// ---------------------------------------------------------------------------
__global__ void k2_scale(const float* __restrict__ Ws, const float* __restrict__ bs,
                         const float* __restrict__ gs, const float* __restrict__ bes,
                         const float* __restrict__ Wl, const float* __restrict__ bl,
                         const float* __restrict__ gl, const float* __restrict__ bel,
                         const float* __restrict__ Wr, const float* __restrict__ br,
                         const float* __restrict__ gr, const float* __restrict__ ber,
                         float* __restrict__ ws) {
    int e = blockIdx.x * 256 + threadIdx.x;
    if (e >= 3 * DOUT) return;
    int p = e / DOUT, j = e - p * DOUT;

    const float* W  = (p == 0) ? Ws  : (p == 1) ? Wl  : Wr;
    const float* b  = (p == 0) ? bs  : (p == 1) ? bl  : br;
    const float* g  = (p == 0) ? gs  : (p == 1) ? gl  : gr;
    const float* be = (p == 0) ? bes : (p == 1) ? bel : ber;

    const float* T = ws + T_OFF + p * T_SIZE + j * DA;
    float eh2 = 0.f;
    for (int k = 0; k < D; k++) eh2 += T[k] * W[j * D + k];
    eh2 += T[D] * b[j];
    const float invN = 1.0f / (float)N_ROWS;
    eh2 *= invN;
    float mu = T[D] * invN;
    float var = eh2 - mu * mu;
    float a = g[j] * rsqrtf(var + EPS);

    float* Wp = ws + WP_OFF + p * WP_SIZE + j * DA;
    for (int k = 0; k < D; k++) Wp[k] = a * W[j * D + k];
    Wp[D] = a * b[j] + be[j] - a * mu;
}

// ---------------------------------------------------------------------------
// K2c: bilinear matrices Mc[q][k*84+i] = sum_j W'_a[j,i] * W'_b[j,k]
//      a = i-side (k3 register vector v), b = k-side (k3 streamed w).
//      q=0: (a=sub,  b=left )  -> s0 = bilin(v=sub,   w=left)
//      q=1: (a=right,b=sub  )  -> s1 = bilin(v=right, w=sub)
//      q=2: (a=left, b=right)  -> s2 = bilin(v=left,  w=right)
// ---------------------------------------------------------------------------
__global__ void k2_M(float* __restrict__ ws) {
    int e = blockIdx.x * 256 + threadIdx.x;
    if (e >= 3 * DA * DA) return;
    int q = e / (DA * DA);
    int rem = e - q * (DA * DA);
    int k = rem / DA, i = rem - k * DA;

    int pa = (q == 1) ? 2 : (q == 2) ? 1 : 0;  // i-side: sub, right, left
    int pb = (q == 1) ? 0 : (q == 0) ? 1 : 2;  // k-side: left, sub,  right
    const float* Wa = ws + WP_OFF + pa * WP_SIZE;
    const float* Wb = ws + WP_OFF + pb * WP_SIZE;

    float a0 = 0.f, a1 = 0.f;
    for (int j = 0; j < DOUT; j += 2) {
        a0 += Wa[j * DA + i] * Wb[j * DA + k];
        a1 += Wa[(j + 1) * DA + i] * Wb[(j + 1) * DA + k];
    }
    ws[MC_OFF + q * MC_SIZE + k * MSTRIDE + i] = a0 + a1;
}

// ---------------------------------------------------------------------------
// K3: per row: 3 bilinear sims -> softmax -> combine.  NO LDS.
//     - M elements flow through the SCALAR path: wave-uniform address ->
//       s_load -> SGPR operand of v_fmac (free broadcast, zero VGPR cost).
//       One lgkmcnt drain per column (~200cy) vs 162cy of FMAs; hidden by
//       4 waves/SIMD (VGPR <= 128 via __launch_bounds__(256,4)).
//     - The ONLY lgkm ops in the loop are the column s_loads (no ds_read!),
//       so the drain is batched, not per-load (round 0's 4400cy/col bug).
//     - w side streamed as own-row float4 global loads: vmcnt-counted
//       (decoupled), stride-320B pattern is L1-resident.
//     - k0 loop kept ROLLED (unroll 1) -> ~12KB code, fits 32KB I$.
// ---------------------------------------------------------------------------
#define K3_TPB 256

__device__ __forceinline__ void pullg(float (&v)[D], const float4* __restrict__ g) {
#pragma unroll
    for (int c = 0; c < D / 4; c++) {
        float4 t = g[c];
        v[c * 4 + 0] = t.x; v[c * 4 + 1] = t.y;
        v[c * 4 + 2] = t.z; v[c * 4 + 3] = t.w;
    }
}

__device__ __forceinline__ float bilin_s(const float* __restrict__ Mc,
                                         const float (&v)[D],
                                         const float4* __restrict__ w4p) {
    float acc0 = 0.f, acc1 = 0.f;
#pragma unroll 1
    for (int k0 = 0; k0 < D / 4; k0++) {     // 20 rolled iters, 4 columns each
        float4 w4 = w4p[k0];                  // per-lane global load (vmcnt)
        float d0, d1, d2, d3;
        {
            const float* __restrict__ col = Mc + (k0 * 4 + 0) * MSTRIDE;  // uniform -> s_load
            float t0 = 0.f, t1 = 0.f, t2 = 0.f, t3 = 0.f;
#pragma unroll
            for (int c = 0; c < D; c += 4) {
                t0 += col[c + 0] * v[c + 0];
                t1 += col[c + 1] * v[c + 1];
                t2 += col[c + 2] * v[c + 2];
                t3 += col[c + 3] * v[c + 3];
            }
            d0 = ((t0 + t1) + (t2 + t3)) + col[D];
        }
        {
            const float* __restrict__ col = Mc + (k0 * 4 + 1) * MSTRIDE;
            float t0 = 0.f, t1 = 0.f, t2 = 0.f, t3 = 0.f;
#pragma unroll
            for (int c = 0; c < D; c += 4) {
                t0 += col[c + 0] * v[c + 0];
                t1 += col[c + 1] * v[c + 1];
                t2 += col[c + 2] * v[c + 2];
                t3 += col[c + 3] * v[c + 3];
            }
            d1 = ((t0 + t1) + (t2 + t3)) + col[D];
        }
        {
            const float* __restrict__ col = Mc + (k0 * 4 + 2) * MSTRIDE;
            float t0 = 0.f, t1 = 0.f, t2 = 0.f, t3 = 0.f;
#pragma unroll
            for (int c = 0; c < D; c += 4) {
                t0 += col[c + 0] * v[c + 0];
                t1 += col[c + 1] * v[c + 1];
                t2 += col[c + 2] * v[c + 2];
                t3 += col[c + 3] * v[c + 3];
            }
            d2 = ((t0 + t1) + (t2 + t3)) + col[D];
        }
        {
            const float* __restrict__ col = Mc + (k0 * 4 + 3) * MSTRIDE;
            float t0 = 0.f, t1 = 0.f, t2 = 0.f, t3 = 0.f;
#pragma unroll
            for (int c = 0; c < D; c += 4) {
                t0 += col[c + 0] * v[c + 0];
                t1 += col[c + 1] * v[c + 1];
                t2 += col[c + 2] * v[c + 2];
                t3 += col[c + 3] * v[c + 3];
            }
            d3 = ((t0 + t1) + (t2 + t3)) + col[D];
        }
        acc0 += d0 * w4.x + d1 * w4.y;
        acc1 += d2 * w4.z + d3 * w4.w;
    }
    {   // k = 80 term (aug element of w~ = 1)
        const float* __restrict__ col = Mc + D * MSTRIDE;
        float t0 = 0.f, t1 = 0.f, t2 = 0.f, t3 = 0.f;
#pragma unroll
        for (int c = 0; c < D; c += 4) {
            t0 += col[c + 0] * v[c + 0];
            t1 += col[c + 1] * v[c + 1];
            t2 += col[c + 2] * v[c + 2];
            t3 += col[c + 3] * v[c + 3];
        }
        acc0 += ((t0 + t1) + (t2 + t3)) + col[D];
    }
    return acc0 + acc1;
}

__global__ __launch_bounds__(K3_TPB, 4) void k3_main(const float* __restrict__ xs_g,
                                                     const float* __restrict__ xl_g,
                                                     const float* __restrict__ xr_g,
                                                     const float* __restrict__ ws,
                                                     float* __restrict__ out) {
    const int r = blockIdx.x * K3_TPB + threadIdx.x;
    const size_t ro = (size_t)r * D;
    const float4* __restrict__ Lrow = reinterpret_cast<const float4*>(xl_g + ro);
    const float4* __restrict__ Rrow = reinterpret_cast<const float4*>(xr_g + ro);
    const float4* __restrict__ Srow = reinterpret_cast<const float4*>(xs_g + ro);

    const float* Msl = ws + MC_OFF + 0 * MC_SIZE;
    const float* Msr = ws + MC_OFF + 1 * MC_SIZE;   // stored transposed (a=right)
    const float* Mlr = ws + MC_OFF + 2 * MC_SIZE;

    float v[D];  // the ONE register vector

    pullg(v, Lrow);                      // v = left
    float s2 = bilin_s(Mlr, v, Rrow);    // (left, right)

    pullg(v, Rrow);                      // v = right (L1-hot: just streamed)
    float s1 = bilin_s(Msr, v, Srow);    // (right, sub)

    pullg(v, Srow);                      // v = sub
    float s0 = bilin_s(Msl, v, Lrow);    // (sub, left)

    // softmax over [s0, s1, s2] -> weights for [left, right, sub]
    float m = fmaxf(s0, fmaxf(s1, s2));
    float e0 = __expf(s0 - m), e1 = __expf(s1 - m), e2 = __expf(s2 - m);
    float inv = 1.0f / (e0 + e1 + e2);
    float p0 = e0 * inv, p1 = e1 * inv, p2 = e2 * inv;

    float4* __restrict__ outp = reinterpret_cast<float4*>(out + ro);
#pragma unroll
    for (int c = 0; c < D / 4; c++) {
        float4 L4 = Lrow[c];
        float4 R4 = Rrow[c];
        float4 o;
        o.x = p0 * L4.x + p1 * R4.x + p2 * v[c * 4 + 0];
        o.y = p0 * L4.y + p1 * R4.y + p2 * v[c * 4 + 1];
        o.z = p0 * L4.z + p1 * R4.z + p2 * v[c * 4 + 2];
        o.w = p0 * L4.w + p1 * R4.w + p2 * v[c * 4 + 3];
        outp[c] = o;
    }
}

// ---------------------------------------------------------------------------
extern "C" void kernel_launch(void* const* d_in, const int* in_sizes, int n_in,
                              void* d_out, int out_size, void* d_ws, size_t ws_size,
                              hipStream_t stream) {
    const float* xs = (const float*)d_in[0];
    const float* xl = (const float*)d_in[1];
    const float* xr = (const float*)d_in[2];
    const float* Wsub = (const float*)d_in[3];
    const float* bsub = (const float*)d_in[4];
    const float* gsub = (const float*)d_in[5];
    const float* besub = (const float*)d_in[6];
    const float* Wleft = (const float*)d_in[7];
    const float* bleft = (const float*)d_in[8];
    const float* gleft = (const float*)d_in[9];
    const float* beleft = (const float*)d_in[10];
    const float* Wright = (const float*)d_in[11];
    const float* bright = (const float*)d_in[12];
    const float* gright = (const float*)d_in[13];
    const float* beright = (const float*)d_in[14];
    float* ws = (float*)d_ws;
    float* out = (float*)d_out;

    hipMemsetAsync(ws + S_OFF, 0, 3 * S_SIZE * sizeof(float), stream);

    k1_moments<<<dim3(K1_BLOCKS, 3), 256, 0, stream>>>(xs, xl, xr, ws);
    k2_T<<<(3 * DOUT * DA + 255) / 256, 256, 0, stream>>>(
        Wsub, bsub, Wleft, bleft, Wright, bright, ws);
    k2_scale<<<(3 * DOUT + 255) / 256, 256, 0, stream>>>(
        Wsub, bsub, gsub, besub, Wleft, bleft, gleft, beleft,
        Wright, bright, gright, beright, ws);
    k2_M<<<(3 * DA * DA + 255) / 256, 256, 0, stream>>>(ws);
    k3_main<<<N_ROWS / K3_TPB, K3_TPB, 0, stream>>>(xs, xl, xr, ws, out);
}

// Round 5
// 699.025 us; speedup vs baseline: 6.7800x; 3.2036x over previous
//
#include <hip/hip_runtime.h>

// Problem constants (fixed by the reference)
#define N_ROWS 262144
#define D 80           // input feature dim
#define DA 81          // augmented dim [x, 1]
#define MSTRIDE 84     // column stride for bilinear matrices
#define DOUT 160
#define EPS 1e-5f

// ws layout (in floats)
#define S_OFF   0                      // 3 x (81*81) second-moment matrices
#define S_SIZE  (DA * DA)              // 6561
#define T_OFF   (3 * S_SIZE)           // T = W~ @ S~  (3 x 160x81)
#define T_SIZE  (DOUT * DA)
#define WP_OFF  (T_OFF + 3 * T_SIZE)   // W' effective weights (3 x 160x81)
#define WP_SIZE (DOUT * DA)
#define MC_OFF  ((WP_OFF + 3 * WP_SIZE + 3) & ~3) // Mc[q][k*84+i] = M_q[i,k]
#define MC_SIZE (DA * MSTRIDE)
#define AUG_OFF (MC_OFF + 3 * MC_SIZE) // aug[q][k] = M_q[i=80, k]  (3 x 84)
#define AUG_SIZE 84

// ---------------------------------------------------------------------------
// K1: per-input augmented second moments S~ = sum_rows [x,1][x,1]^T
//     Double-buffered LDS staging, 512 blocks/input. (unchanged this round)
// ---------------------------------------------------------------------------
#define K1_BLOCKS 512
#define K1_ROWS   (N_ROWS / K1_BLOCKS)   // 512 rows/block
#define K1_NT     (K1_ROWS / 32)         // 16 tiles of 32 rows

__global__ __launch_bounds__(256) void k1_moments(const float* __restrict__ xs,
                                                  const float* __restrict__ xl,
                                                  const float* __restrict__ xr,
                                                  float* __restrict__ ws) {
    const float* x = (blockIdx.y == 0) ? xs : (blockIdx.y == 1) ? xl : xr;
    float* S = ws + S_OFF + blockIdx.y * S_SIZE;

    __shared__ float lds[2 * 2560 + 3600];   // 34.9 KB

    const int tid = threadIdx.x;
    const int wave = tid >> 6;
    const int lane = tid & 63;

    int ti = -1, tj = -1;
    if (lane < 55) {
        int l = lane, a = 0;
        while (l >= 10 - a) { l -= 10 - a; a++; }
        ti = a; tj = a + l;
    }

    float acc[8][8];
#pragma unroll
    for (int u = 0; u < 8; u++)
#pragma unroll
        for (int v = 0; v < 8; v++) acc[u][v] = 0.f;
    float csum[8];
#pragma unroll
    for (int u = 0; u < 8; u++) csum[u] = 0.f;

    const size_t base = (size_t)blockIdx.x * K1_ROWS * D;
    const float4* __restrict__ gsrc = reinterpret_cast<const float4*>(x + base);

    float4 r0, r1, r2;
    r0 = gsrc[tid]; r1 = gsrc[tid + 256]; if (tid < 128) r2 = gsrc[tid + 512];
    {
        float4* d4 = reinterpret_cast<float4*>(lds);
        d4[tid] = r0; d4[tid + 256] = r1; if (tid < 128) d4[tid + 512] = r2;
    }

    for (int t = 0; t < K1_NT; t++) {
        __syncthreads();
        if (t + 1 < K1_NT) {
            const float4* __restrict__ s = gsrc + (size_t)(t + 1) * 640;
            r0 = s[tid]; r1 = s[tid + 256]; if (tid < 128) r2 = s[tid + 512];
        }
        const float* __restrict__ buf = lds + (t & 1) * 2560;
        if (ti >= 0) {
            const int rbase = wave * 8;
#pragma unroll 2
            for (int rr = 0; rr < 8; rr++) {
                const float* row = &buf[(rbase + rr) * D];
                float a8[8], b8[8];
                *reinterpret_cast<float4*>(&a8[0]) = *reinterpret_cast<const float4*>(&row[ti * 8]);
                *reinterpret_cast<float4*>(&a8[4]) = *reinterpret_cast<const float4*>(&row[ti * 8 + 4]);
                *reinterpret_cast<float4*>(&b8[0]) = *reinterpret_cast<const float4*>(&row[tj * 8]);
                *reinterpret_cast<float4*>(&b8[4]) = *reinterpret_cast<const float4*>(&row[tj * 8 + 4]);
#pragma unroll
                for (int u = 0; u < 8; u++)
#pragma unroll
                    for (int v = 0; v < 8; v++) acc[u][v] += a8[u] * b8[v];
                if (ti == tj) {
#pragma unroll
                    for (int u = 0; u < 8; u++) csum[u] += a8[u];
                }
            }
        }
        if (t + 1 < K1_NT) {
            float4* d4 = reinterpret_cast<float4*>(lds + ((t + 1) & 1) * 2560);
            d4[tid] = r0; d4[tid + 256] = r1; if (tid < 128) d4[tid + 512] = r2;
        }
    }

    float* red = lds + 5120;
    __syncthreads();
    for (int i = tid; i < 3600; i += 256) red[i] = 0.f;
    __syncthreads();
    for (int w = 0; w < 4; w++) {
        if (wave == w && ti >= 0) {
            float* dst = &red[lane * 64];
#pragma unroll
            for (int u = 0; u < 8; u++)
#pragma unroll
                for (int v = 0; v < 8; v++) dst[u * 8 + v] += acc[u][v];
            if (ti == tj) {
#pragma unroll
                for (int u = 0; u < 8; u++) red[3520 + ti * 8 + u] += csum[u];
            }
        }
        __syncthreads();
    }

    for (int e = tid; e < 3520; e += 256) {
        int p = e >> 6, o = e & 63;
        int l = p, a = 0;
        while (l >= 10 - a) { l -= 10 - a; a++; }
        const int pi = a, pj = a + l;
        const int i = pi * 8 + (o >> 3), j = pj * 8 + (o & 7);
        const float v = red[e];
        atomicAdd(&S[i * DA + j], v);
        if (pi != pj) atomicAdd(&S[j * DA + i], v);
    }
    for (int c = tid; c < D; c += 256) {
        const float v = red[3520 + c];
        atomicAdd(&S[c * DA + D], v);
        atomicAdd(&S[D * DA + c], v);
    }
    // corner S[80,80] = N handled inline in k2_T
}

// ---------------------------------------------------------------------------
// K2a: T[p][j][i] = sum_k W~[j,k] * S~[k,i]   (W~ = [W | b])
// ---------------------------------------------------------------------------
__global__ void k2_T(const float* __restrict__ Ws, const float* __restrict__ bs,
                     const float* __restrict__ Wl, const float* __restrict__ bl,
                     const float* __restrict__ Wr, const float* __restrict__ br,
                     float* __restrict__ ws) {
    int e = blockIdx.x * 256 + threadIdx.x;
    if (e >= 3 * DOUT * DA) return;
    int p = e / (DOUT * DA);
    int rem = e - p * (DOUT * DA);
    int j = rem / DA, i = rem - j * DA;

    const float* W = (p == 0) ? Ws : (p == 1) ? Wl : Wr;
    const float* b = (p == 0) ? bs : (p == 1) ? bl : br;
    const float* S = ws + S_OFF + p * S_SIZE;

    float a0 = 0.f, a1 = 0.f;
    for (int k = 0; k < D; k += 2) {
        a0 += W[j * D + k] * S[k * DA + i];
        a1 += W[j * D + k + 1] * S[(k + 1) * DA + i];
    }
    float s80 = (i == D) ? (float)N_ROWS : S[D * DA + i];
    ws[T_OFF + p * T_SIZE + j * DA + i] = a0 + a1 + b[j] * s80;
}

// ---------------------------------------------------------------------------
// K2b: per feature j: mu, var, a -> effective W'[j,:] (augmented)
// ---------------------------------------------------------------------------
__global__ void k2_scale(const float* __restrict__ Ws, const float* __restrict__ bs,
                         const float* __restrict__ gs, const float* __restrict__ bes,
                         const float* __restrict__ Wl, const float* __restrict__ bl,
                         const float* __restrict__ gl, const float* __restrict__ bel,
                         const float* __restrict__ Wr, const float* __restrict__ br,
                         const float* __restrict__ gr, const float* __restrict__ ber,
                         float* __restrict__ ws) {
    int e = blockIdx.x * 256 + threadIdx.x;
    if (e >= 3 * DOUT) return;
    int p = e / DOUT, j = e - p * DOUT;

    const float* W  = (p == 0) ? Ws  : (p == 1) ? Wl  : Wr;
    const float* b  = (p == 0) ? bs  : (p == 1) ? bl  : br;
    const float* g  = (p == 0) ? gs  : (p == 1) ? gl  : gr;
    const float* be = (p == 0) ? bes : (p == 1) ? bel : ber;

    const float* T = ws + T_OFF + p * T_SIZE + j * DA;
    float eh2 = 0.f;
    for (int k = 0; k < D; k++) eh2 += T[k] * W[j * D + k];
    eh2 += T[D] * b[j];
    const float invN = 1.0f / (float)N_ROWS;
    eh2 *= invN;
    float mu = T[D] * invN;
    float var = eh2 - mu * mu;
    float a = g[j] * rsqrtf(var + EPS);

    float* Wp = ws + WP_OFF + p * WP_SIZE + j * DA;
    for (int k = 0; k < D; k++) Wp[k] = a * W[j * D + k];
    Wp[D] = a * b[j] + be[j] - a * mu;
}

// ---------------------------------------------------------------------------
// K2c: bilinear matrices Mc[q][k*84+i] = M_q[i,k] = sum_j W'_a[j,i] * W'_b[j,k]
//      a = i-side (dot operand), b = k-side (GEMM operand in k3).
//      q=0: (a=sub,  b=left )   q=1: (a=sub, b=right)   q=2: (a=left, b=right)
//      Also emits the compact aug row aug[q][k] = M_q[80,k] for k3's epilogue.
// ---------------------------------------------------------------------------
__global__ void k2_M(float* __restrict__ ws) {
    int e = blockIdx.x * 256 + threadIdx.x;
    if (e >= 3 * DA * DA) return;
    int q = e / (DA * DA);
    int rem = e - q * (DA * DA);
    int k = rem / DA, i = rem - k * DA;

    int pa = (q == 2) ? 1 : 0;  // i-side: sub, sub, left
    int pb = (q == 0) ? 1 : 2;  // k-side: left, right, right
    const float* Wa = ws + WP_OFF + pa * WP_SIZE;
    const float* Wb = ws + WP_OFF + pb * WP_SIZE;

    float a0 = 0.f, a1 = 0.f;
    for (int j = 0; j < DOUT; j += 2) {
        a0 += Wa[j * DA + i] * Wb[j * DA + k];
        a1 += Wa[(j + 1) * DA + i] * Wb[(j + 1) * DA + k];
    }
    float v = a0 + a1;
    ws[MC_OFF + q * MC_SIZE + k * MSTRIDE + i] = v;
    if (i == D) ws[AUG_OFF + q * AUG_SIZE + k] = v;   // row i=80 compact copy
}

// ---------------------------------------------------------------------------
// K3 (rewritten as a fused tiled GEMM):
//     s_q[r] = x_a~[r]^T M_q x_b~[r]  =  sum_{i<80} x_a[r,i] * Z_q[r,i]
//              + sum_{k<=80} M_q[80,k] * x_b~[r,k]
//     where Z_q[r,i] = sum_{k<80} M_q[i,k] x_b[r,k] + M_q[i,80].
//
//     Structure: 64 rows/block, 320 threads = 20 i-groups x 16 row-groups.
//     Each thread owns a 4-row x 4-col Z tile (16 accumulators) -- per-thread
//     register state ~70 VGPRs, so the allocator CANNOT be forced to spill
//     (rounds 0/1/2/4 all died on one-thread-holds-80-floats pressure).
//     k-side X (left,right) staged once in LDS [64][84] (pad -> <=2-way bank
//     aliasing = free) with 21x reuse; M streamed from global as float4 rows
//     of Mc (27 KB/matrix, L1-resident). Dot partials reduced via LDS;
//     softmax + combine fused; all global I/O coalesced float4.
// ---------------------------------------------------------------------------
#define G_IG   20
#define G_RG   16
#define G_RT   4
#define G_ROWS (G_RG * G_RT)        // 64
#define G_TPB  (G_IG * G_RG)        // 320
#define XLD    84                    // padded LDS row stride (floats)

__device__ __forceinline__ void gemm_partial(const float* __restrict__ Mc,
                                             const float* __restrict__ Xk,   // LDS k-side, stride XLD
                                             const float* __restrict__ dotb, // i-side rows base
                                             int dotStride,
                                             int ig, int rg,
                                             float* __restrict__ sred) {
    const int i0 = ig * 4;
    float z[G_RT][4];
#pragma unroll
    for (int r = 0; r < G_RT; r++) { z[r][0] = z[r][1] = z[r][2] = z[r][3] = 0.f; }

#pragma unroll 2
    for (int kb = 0; kb < 20; kb++) {
        float4 m[4];
#pragma unroll
        for (int j = 0; j < 4; j++)
            m[j] = *reinterpret_cast<const float4*>(&Mc[(kb * 4 + j) * MSTRIDE + i0]);
#pragma unroll
        for (int r = 0; r < G_RT; r++) {
            float4 xk = *reinterpret_cast<const float4*>(&Xk[(rg * G_RT + r) * XLD + kb * 4]);
            z[r][0] += m[0].x * xk.x; z[r][1] += m[0].y * xk.x; z[r][2] += m[0].z * xk.x; z[r][3] += m[0].w * xk.x;
            z[r][0] += m[1].x * xk.y; z[r][1] += m[1].y * xk.y; z[r][2] += m[1].z * xk.y; z[r][3] += m[1].w * xk.y;
            z[r][0] += m[2].x * xk.z; z[r][1] += m[2].y * xk.z; z[r][2] += m[2].z * xk.z; z[r][3] += m[2].w * xk.z;
            z[r][0] += m[3].x * xk.w; z[r][1] += m[3].y * xk.w; z[r][2] += m[3].z * xk.w; z[r][3] += m[3].w * xk.w;
        }
    }
    {   // k = 80 tail: x_b~[r,80] = 1
        float4 m80 = *reinterpret_cast<const float4*>(&Mc[D * MSTRIDE + i0]);
#pragma unroll
        for (int r = 0; r < G_RT; r++) {
            z[r][0] += m80.x; z[r][1] += m80.y; z[r][2] += m80.z; z[r][3] += m80.w;
        }
    }
    // dot with i-side rows, write per-(row, ig) partial
#pragma unroll
    for (int r = 0; r < G_RT; r++) {
        const int row = rg * G_RT + r;
        float4 w4 = *reinterpret_cast<const float4*>(&dotb[(size_t)row * dotStride + i0]);
        sred[row * 21 + ig] = z[r][0] * w4.x + z[r][1] * w4.y + z[r][2] * w4.z + z[r][3] * w4.w;
    }
}

__global__ __launch_bounds__(G_TPB, 4) void k3_main(const float* __restrict__ xs_g,
                                                    const float* __restrict__ xl_g,
                                                    const float* __restrict__ xr_g,
                                                    const float* __restrict__ ws,
                                                    float* __restrict__ out) {
    __shared__ float Xl[G_ROWS * XLD];
    __shared__ float Xr[G_ROWS * XLD];
    __shared__ float sred[G_ROWS * 21];
    __shared__ float parr[G_ROWS * 4];
    __shared__ float augl[3 * AUG_SIZE];

    const int tid = threadIdx.x;
    const int ig = tid % G_IG;
    const int rg = tid / G_IG;
    const size_t rowBase = (size_t)blockIdx.x * G_ROWS;

    const float* Mc0 = ws + MC_OFF + 0 * MC_SIZE;
    const float* Mc1 = ws + MC_OFF + 1 * MC_SIZE;
    const float* Mc2 = ws + MC_OFF + 2 * MC_SIZE;
    const float* subb = xs_g + rowBase * D;

    // ---- stage left/right tiles + aug rows ----
    {
        const float4* gl = reinterpret_cast<const float4*>(xl_g + rowBase * D);
        const float4* gr = reinterpret_cast<const float4*>(xr_g + rowBase * D);
#pragma unroll
        for (int it = 0; it < 4; it++) {
            int u = tid + it * G_TPB;          // < 1280
            int r = u / 20, c = u % 20;
            *reinterpret_cast<float4*>(&Xl[r * XLD + c * 4]) = gl[u];
            *reinterpret_cast<float4*>(&Xr[r * XLD + c * 4]) = gr[u];
        }
        if (tid < 3 * AUG_SIZE) augl[tid] = ws[AUG_OFF + tid];
    }
    __syncthreads();

    float s0r = 0.f, s1r = 0.f, s2r = 0.f;   // meaningful on tid < 64 only

    // ---- sim 0: M_sl, gemm side = left (LDS), dot side = sub (global) ----
    gemm_partial(Mc0, Xl, subb, D, ig, rg, sred);
    __syncthreads();
    if (tid < G_ROWS) {
        float a = 0.f;
#pragma unroll
        for (int c = 0; c < 20; c++) a += sred[tid * 21 + c];
        float b = augl[0 * AUG_SIZE + D];
#pragma unroll
        for (int c = 0; c < 20; c++) {
            float4 u4 = *reinterpret_cast<const float4*>(&augl[0 * AUG_SIZE + c * 4]);
            float4 x4 = *reinterpret_cast<const float4*>(&Xl[tid * XLD + c * 4]);
            b += u4.x * x4.x + u4.y * x4.y + u4.z * x4.z + u4.w * x4.w;
        }
        s0r = a + b;
    }
    __syncthreads();

    // ---- sim 1: M_sr, gemm side = right (LDS), dot side = sub (global) ----
    gemm_partial(Mc1, Xr, subb, D, ig, rg, sred);
    __syncthreads();
    if (tid < G_ROWS) {
        float a = 0.f;
#pragma unroll
        for (int c = 0; c < 20; c++) a += sred[tid * 21 + c];
        float b = augl[1 * AUG_SIZE + D];
#pragma unroll
        for (int c = 0; c < 20; c++) {
            float4 u4 = *reinterpret_cast<const float4*>(&augl[1 * AUG_SIZE + c * 4]);
            float4 x4 = *reinterpret_cast<const float4*>(&Xr[tid * XLD + c * 4]);
            b += u4.x * x4.x + u4.y * x4.y + u4.z * x4.z + u4.w * x4.w;
        }
        s1r = a + b;
    }
    __syncthreads();

    // ---- sim 2: M_lr, gemm side = right (LDS), dot side = left (LDS) ----
    gemm_partial(Mc2, Xr, Xl, XLD, ig, rg, sred);
    __syncthreads();
    if (tid < G_ROWS) {
        float a = 0.f;
#pragma unroll
        for (int c = 0; c < 20; c++) a += sred[tid * 21 + c];
        float b = augl[2 * AUG_SIZE + D];
#pragma unroll
        for (int c = 0; c < 20; c++) {
            float4 u4 = *reinterpret_cast<const float4*>(&augl[2 * AUG_SIZE + c * 4]);
            float4 x4 = *reinterpret_cast<const float4*>(&Xr[tid * XLD + c * 4]);
            b += u4.x * x4.x + u4.y * x4.y + u4.z * x4.z + u4.w * x4.w;
        }
        s2r = a + b;

        // softmax over [s0,s1,s2] -> weights for [left, right, sub]
        float m = fmaxf(s0r, fmaxf(s1r, s2r));
        float e0 = __expf(s0r - m), e1 = __expf(s1r - m), e2 = __expf(s2r - m);
        float inv = 1.0f / (e0 + e1 + e2);
        parr[tid * 4 + 0] = e0 * inv;
        parr[tid * 4 + 1] = e1 * inv;
        parr[tid * 4 + 2] = e2 * inv;
    }
    __syncthreads();

    // ---- combine + store (coalesced) ----
    {
        const float4* gs = reinterpret_cast<const float4*>(subb);
        float4* go = reinterpret_cast<float4*>(out + rowBase * D);
#pragma unroll
        for (int it = 0; it < 4; it++) {
            int u = tid + it * G_TPB;
            int r = u / 20, c = u % 20;
            float p0 = parr[r * 4 + 0], p1 = parr[r * 4 + 1], p2 = parr[r * 4 + 2];
            float4 L = *reinterpret_cast<const float4*>(&Xl[r * XLD + c * 4]);
            float4 R = *reinterpret_cast<const float4*>(&Xr[r * XLD + c * 4]);
            float4 S = gs[u];
            float4 o;
            o.x = p0 * L.x + p1 * R.x + p2 * S.x;
            o.y = p0 * L.y + p1 * R.y + p2 * S.y;
            o.z = p0 * L.z + p1 * R.z + p2 * S.z;
            o.w = p0 * L.w + p1 * R.w + p2 * S.w;
            go[u] = o;
        }
    }
}

// ---------------------------------------------------------------------------
extern "C" void kernel_launch(void* const* d_in, const int* in_sizes, int n_in,
                              void* d_out, int out_size, void* d_ws, size_t ws_size,
                              hipStream_t stream) {
    const float* xs = (const float*)d_in[0];
    const float* xl = (const float*)d_in[1];
    const float* xr = (const float*)d_in[2];
    const float* Wsub = (const float*)d_in[3];
    const float* bsub = (const float*)d_in[4];
    const float* gsub = (const float*)d_in[5];
    const float* besub = (const float*)d_in[6];
    const float* Wleft = (const float*)d_in[7];
    const float* bleft = (const float*)d_in[8];
    const float* gleft = (const float*)d_in[9];
    const float* beleft = (const float*)d_in[10];
    const float* Wright = (const float*)d_in[11];
    const float* bright = (const float*)d_in[12];
    const float* gright = (const float*)d_in[13];
    const float* beright = (const float*)d_in[14];
    float* ws = (float*)d_ws;
    float* out = (float*)d_out;

    hipMemsetAsync(ws + S_OFF, 0, 3 * S_SIZE * sizeof(float), stream);

    k1_moments<<<dim3(K1_BLOCKS, 3), 256, 0, stream>>>(xs, xl, xr, ws);
    k2_T<<<(3 * DOUT * DA + 255) / 256, 256, 0, stream>>>(
        Wsub, bsub, Wleft, bleft, Wright, bright, ws);
    k2_scale<<<(3 * DOUT + 255) / 256, 256, 0, stream>>>(
        Wsub, bsub, gsub, besub, Wleft, bleft, gleft, beleft,
        Wright, bright, gright, beright, ws);
    k2_M<<<(3 * DA * DA + 255) / 256, 256, 0, stream>>>(ws);
    k3_main<<<N_ROWS / G_ROWS, G_TPB, 0, stream>>>(xs, xl, xr, ws, out);
}

// Round 6
// 670.872 us; speedup vs baseline: 7.0645x; 1.0420x over previous
//
#include <hip/hip_runtime.h>

// Problem constants (fixed by the reference)
#define N_ROWS 262144
#define D 80           // input feature dim
#define DA 81          // augmented dim [x, 1]
#define MSTRIDE 84     // column stride for bilinear matrices
#define DOUT 160
#define EPS 1e-5f

// ws layout (in floats)
#define S_OFF   0                      // 3 x (81*81) second-moment matrices (UPPER TRIANGLE valid)
#define S_SIZE  (DA * DA)              // 6561
#define T_OFF   (3 * S_SIZE)           // T = W~ @ S~  (3 x 160x81)
#define T_SIZE  (DOUT * DA)
#define WP_OFF  (T_OFF + 3 * T_SIZE)   // W' effective weights (3 x 160x81)
#define WP_SIZE (DOUT * DA)
#define MC_OFF  ((WP_OFF + 3 * WP_SIZE + 3) & ~3) // Mc[q][k*84+i] = M_q[i,k]
#define MC_SIZE (DA * MSTRIDE)
#define AUG_OFF (MC_OFF + 3 * MC_SIZE) // aug[q][k] = M_q[i=80, k]  (3 x 84)
#define AUG_SIZE 84

// ---------------------------------------------------------------------------
// K1: per-input augmented second moments S~ = sum_rows [x,1][x,1]^T
//     Double-buffered LDS staging, 512 blocks/input.
//     This round: UPPER-TRIANGLE-ONLY atomics (mirror writes dropped, -45%
//     atomic ops); k2_T reads S[min,max] instead.
// ---------------------------------------------------------------------------
#define K1_BLOCKS 512
#define K1_ROWS   (N_ROWS / K1_BLOCKS)   // 512 rows/block
#define K1_NT     (K1_ROWS / 32)         // 16 tiles of 32 rows

__global__ __launch_bounds__(256) void k1_moments(const float* __restrict__ xs,
                                                  const float* __restrict__ xl,
                                                  const float* __restrict__ xr,
                                                  float* __restrict__ ws) {
    const float* x = (blockIdx.y == 0) ? xs : (blockIdx.y == 1) ? xl : xr;
    float* S = ws + S_OFF + blockIdx.y * S_SIZE;

    __shared__ float lds[2 * 2560 + 3600];   // 34.9 KB

    const int tid = threadIdx.x;
    const int wave = tid >> 6;
    const int lane = tid & 63;

    int ti = -1, tj = -1;
    if (lane < 55) {
        int l = lane, a = 0;
        while (l >= 10 - a) { l -= 10 - a; a++; }
        ti = a; tj = a + l;
    }

    float acc[8][8];
#pragma unroll
    for (int u = 0; u < 8; u++)
#pragma unroll
        for (int v = 0; v < 8; v++) acc[u][v] = 0.f;
    float csum[8];
#pragma unroll
    for (int u = 0; u < 8; u++) csum[u] = 0.f;

    const size_t base = (size_t)blockIdx.x * K1_ROWS * D;
    const float4* __restrict__ gsrc = reinterpret_cast<const float4*>(x + base);

    float4 r0, r1, r2;
    r0 = gsrc[tid]; r1 = gsrc[tid + 256]; if (tid < 128) r2 = gsrc[tid + 512];
    {
        float4* d4 = reinterpret_cast<float4*>(lds);
        d4[tid] = r0; d4[tid + 256] = r1; if (tid < 128) d4[tid + 512] = r2;
    }

    for (int t = 0; t < K1_NT; t++) {
        __syncthreads();
        if (t + 1 < K1_NT) {
            const float4* __restrict__ s = gsrc + (size_t)(t + 1) * 640;
            r0 = s[tid]; r1 = s[tid + 256]; if (tid < 128) r2 = s[tid + 512];
        }
        const float* __restrict__ buf = lds + (t & 1) * 2560;
        if (ti >= 0) {
            const int rbase = wave * 8;
#pragma unroll 2
            for (int rr = 0; rr < 8; rr++) {
                const float* row = &buf[(rbase + rr) * D];
                float a8[8], b8[8];
                *reinterpret_cast<float4*>(&a8[0]) = *reinterpret_cast<const float4*>(&row[ti * 8]);
                *reinterpret_cast<float4*>(&a8[4]) = *reinterpret_cast<const float4*>(&row[ti * 8 + 4]);
                *reinterpret_cast<float4*>(&b8[0]) = *reinterpret_cast<const float4*>(&row[tj * 8]);
                *reinterpret_cast<float4*>(&b8[4]) = *reinterpret_cast<const float4*>(&row[tj * 8 + 4]);
#pragma unroll
                for (int u = 0; u < 8; u++)
#pragma unroll
                    for (int v = 0; v < 8; v++) acc[u][v] += a8[u] * b8[v];
                if (ti == tj) {
#pragma unroll
                    for (int u = 0; u < 8; u++) csum[u] += a8[u];
                }
            }
        }
        if (t + 1 < K1_NT) {
            float4* d4 = reinterpret_cast<float4*>(lds + ((t + 1) & 1) * 2560);
            d4[tid] = r0; d4[tid + 256] = r1; if (tid < 128) d4[tid + 512] = r2;
        }
    }

    float* red = lds + 5120;
    __syncthreads();
    for (int i = tid; i < 3600; i += 256) red[i] = 0.f;
    __syncthreads();
    for (int w = 0; w < 4; w++) {
        if (wave == w && ti >= 0) {
            float* dst = &red[lane * 64];
#pragma unroll
            for (int u = 0; u < 8; u++)
#pragma unroll
                for (int v = 0; v < 8; v++) dst[u * 8 + v] += acc[u][v];
            if (ti == tj) {
#pragma unroll
                for (int u = 0; u < 8; u++) red[3520 + ti * 8 + u] += csum[u];
            }
        }
        __syncthreads();
    }

    // global atomics: UPPER TRIANGLE ONLY (no mirrors)
    for (int e = tid; e < 3520; e += 256) {
        int p = e >> 6, o = e & 63;
        int l = p, a = 0;
        while (l >= 10 - a) { l -= 10 - a; a++; }
        const int pi = a, pj = a + l;
        const int i = pi * 8 + (o >> 3), j = pj * 8 + (o & 7);
        atomicAdd(&S[i * DA + j], red[e]);
    }
    for (int c = tid; c < D; c += 256) {
        atomicAdd(&S[c * DA + D], red[3520 + c]);  // column 80 (upper)
    }
    // corner S[80,80] = N handled inline in k2_T
}

// ---------------------------------------------------------------------------
// K2a: T[p][j][i] = sum_k W~[j,k] * S~[k,i]   (W~ = [W | b])
//      S is stored upper-triangle-only: S~[k,i] = S[min(k,i)*DA + max(k,i)]
// ---------------------------------------------------------------------------
__global__ void k2_T(const float* __restrict__ Ws, const float* __restrict__ bs,
                     const float* __restrict__ Wl, const float* __restrict__ bl,
                     const float* __restrict__ Wr, const float* __restrict__ br,
                     float* __restrict__ ws) {
    int e = blockIdx.x * 256 + threadIdx.x;
    if (e >= 3 * DOUT * DA) return;
    int p = e / (DOUT * DA);
    int rem = e - p * (DOUT * DA);
    int j = rem / DA, i = rem - j * DA;

    const float* W = (p == 0) ? Ws : (p == 1) ? Wl : Wr;
    const float* b = (p == 0) ? bs : (p == 1) ? bl : br;
    const float* S = ws + S_OFF + p * S_SIZE;

    float a0 = 0.f;
    const int kmid = (i < D) ? (i + 1) : D;
    for (int k = 0; k < kmid; k++)          // k <= i: (k,i) is upper
        a0 += W[j * D + k] * S[k * DA + i];
    for (int k = kmid; k < D; k++)          // k > i: read (i,k)
        a0 += W[j * D + k] * S[i * DA + k];
    float s80 = (i == D) ? (float)N_ROWS : S[i * DA + D];
    ws[T_OFF + p * T_SIZE + j * DA + i] = a0 + b[j] * s80;
}

// ---------------------------------------------------------------------------
// K2b: per feature j: mu, var, a -> effective W'[j,:] (augmented)
// ---------------------------------------------------------------------------
__global__ void k2_scale(const float* __restrict__ Ws, const float* __restrict__ bs,
                         const float* __restrict__ gs, const float* __restrict__ bes,
                         const float* __restrict__ Wl, const float* __restrict__ bl,
                         const float* __restrict__ gl, const float* __restrict__ bel,
                         const float* __restrict__ Wr, const float* __restrict__ br,
                         const float* __restrict__ gr, const float* __restrict__ ber,
                         float* __restrict__ ws) {
    int e = blockIdx.x * 256 + threadIdx.x;
    if (e >= 3 * DOUT) return;
    int p = e / DOUT, j = e - p * DOUT;

    const float* W  = (p == 0) ? Ws  : (p == 1) ? Wl  : Wr;
    const float* b  = (p == 0) ? bs  : (p == 1) ? bl  : br;
    const float* g  = (p == 0) ? gs  : (p == 1) ? gl  : gr;
    const float* be = (p == 0) ? bes : (p == 1) ? bel : ber;

    const float* T = ws + T_OFF + p * T_SIZE + j * DA;
    float eh2 = 0.f;
    for (int k = 0; k < D; k++) eh2 += T[k] * W[j * D + k];
    eh2 += T[D] * b[j];
    const float invN = 1.0f / (float)N_ROWS;
    eh2 *= invN;
    float mu = T[D] * invN;
    float var = eh2 - mu * mu;
    float a = g[j] * rsqrtf(var + EPS);

    float* Wp = ws + WP_OFF + p * WP_SIZE + j * DA;
    for (int k = 0; k < D; k++) Wp[k] = a * W[j * D + k];
    Wp[D] = a * b[j] + be[j] - a * mu;
}

// ---------------------------------------------------------------------------
// K2c: bilinear matrices Mc[q][k*84+i] = M_q[i,k] = sum_j W'_a[j,i] * W'_b[j,k]
//      q=0: (a=sub,  b=left )   q=1: (a=sub, b=right)   q=2: (a=left, b=right)
//      Also emits the compact aug row aug[q][k] = M_q[80,k].
// ---------------------------------------------------------------------------
__global__ void k2_M(float* __restrict__ ws) {
    int e = blockIdx.x * 256 + threadIdx.x;
    if (e >= 3 * DA * DA) return;
    int q = e / (DA * DA);
    int rem = e - q * (DA * DA);
    int k = rem / DA, i = rem - k * DA;

    int pa = (q == 2) ? 1 : 0;  // i-side: sub, sub, left
    int pb = (q == 0) ? 1 : 2;  // k-side: left, right, right
    const float* Wa = ws + WP_OFF + pa * WP_SIZE;
    const float* Wb = ws + WP_OFF + pb * WP_SIZE;

    float a0 = 0.f, a1 = 0.f;
    for (int j = 0; j < DOUT; j += 2) {
        a0 += Wa[j * DA + i] * Wb[j * DA + k];
        a1 += Wa[(j + 1) * DA + i] * Wb[(j + 1) * DA + k];
    }
    float v = a0 + a1;
    ws[MC_OFF + q * MC_SIZE + k * MSTRIDE + i] = v;
    if (i == D) ws[AUG_OFF + q * AUG_SIZE + k] = v;   // row i=80 compact copy
}

// ---------------------------------------------------------------------------
// K3 (fused tiled GEMM, v2):
//     s_q[r] = sum_{i<80} x_a[r,i] * Z_q[r,i]
//              + sum_{k<80} M_q[80,k]*x_b[r,k] + M_q[80,80]
//     Z_q[r,i] = sum_{k<80} M_q[i,k] x_b[r,k] + M_q[i,80]
//
//     v2 changes vs round 5 (which verified the structure):
//       - ONE staged X tile (k-side only; 21.5 KB) instead of Xl+Xr: the
//         aug dot is folded into the GEMM partials so reduce phases never
//         touch X -> re-stage overlaps the s0 reduce.  LDS 50.7 -> 32.5 KB
//         => 5 blocks/CU (was 3): more waves to hide M-load latency.
//       - g1/g2 passes back-to-back with NO barrier (disjoint sred buffers,
//         per-thread-private slots).  Barriers 9 -> 6.
//       - aug chunk read per-thread from global (L1-hot), no LDS copy.
// ---------------------------------------------------------------------------
#define G_IG   20
#define G_RG   16
#define G_RT   4
#define G_ROWS (G_RG * G_RT)        // 64
#define G_TPB  (G_IG * G_RG)        // 320
#define XLD    84                   // padded LDS row stride (floats)
#define SRED_LD 20

__device__ __forceinline__ void gemm_pass(const float* __restrict__ Mc,
                                          const float* __restrict__ augq,  // ws+AUG_OFF+q*AUG_SIZE
                                          const float* __restrict__ X,     // LDS k-side tile
                                          const float4* __restrict__ dot4, // global i-side rows (20 float4/row)
                                          int ig, int rg,
                                          float* __restrict__ sred) {
    const int i0 = ig * 4;
    float z[G_RT][4];
#pragma unroll
    for (int r = 0; r < G_RT; r++) { z[r][0] = z[r][1] = z[r][2] = z[r][3] = 0.f; }

#pragma unroll 2
    for (int kb = 0; kb < 20; kb++) {
        float4 m0 = *reinterpret_cast<const float4*>(&Mc[(kb * 4 + 0) * MSTRIDE + i0]);
        float4 m1 = *reinterpret_cast<const float4*>(&Mc[(kb * 4 + 1) * MSTRIDE + i0]);
        float4 m2 = *reinterpret_cast<const float4*>(&Mc[(kb * 4 + 2) * MSTRIDE + i0]);
        float4 m3 = *reinterpret_cast<const float4*>(&Mc[(kb * 4 + 3) * MSTRIDE + i0]);
#pragma unroll
        for (int r = 0; r < G_RT; r++) {
            float4 xk = *reinterpret_cast<const float4*>(&X[(rg * G_RT + r) * XLD + kb * 4]);
            z[r][0] += m0.x * xk.x; z[r][1] += m0.y * xk.x; z[r][2] += m0.z * xk.x; z[r][3] += m0.w * xk.x;
            z[r][0] += m1.x * xk.y; z[r][1] += m1.y * xk.y; z[r][2] += m1.z * xk.y; z[r][3] += m1.w * xk.y;
            z[r][0] += m2.x * xk.z; z[r][1] += m2.y * xk.z; z[r][2] += m2.z * xk.z; z[r][3] += m2.w * xk.z;
            z[r][0] += m3.x * xk.w; z[r][1] += m3.y * xk.w; z[r][2] += m3.z * xk.w; z[r][3] += m3.w * xk.w;
        }
    }
    {   // k = 80 column term (x_b~[r,80] = 1)
        float4 m80 = *reinterpret_cast<const float4*>(&Mc[D * MSTRIDE + i0]);
#pragma unroll
        for (int r = 0; r < G_RT; r++) {
            z[r][0] += m80.x; z[r][1] += m80.y; z[r][2] += m80.z; z[r][3] += m80.w;
        }
    }
    // dot with i-side rows + fold this thread's aug-row chunk; write partial
    float4 av = *reinterpret_cast<const float4*>(&augq[i0]);   // global, L1-hot
#pragma unroll
    for (int r = 0; r < G_RT; r++) {
        const int row = rg * G_RT + r;
        float4 xa = *reinterpret_cast<const float4*>(&X[row * XLD + i0]);
        float4 w4 = dot4[row * 20 + ig];
        sred[row * SRED_LD + ig] =
            z[r][0] * w4.x + z[r][1] * w4.y + z[r][2] * w4.z + z[r][3] * w4.w
            + av.x * xa.x + av.y * xa.y + av.z * xa.z + av.w * xa.w;
    }
}

__global__ __launch_bounds__(G_TPB, 5) void k3_main(const float* __restrict__ xs_g,
                                                    const float* __restrict__ xl_g,
                                                    const float* __restrict__ xr_g,
                                                    const float* __restrict__ ws,
                                                    float* __restrict__ out) {
    __shared__ __align__(16) float X[G_ROWS * XLD];          // 21504 B
    __shared__ __align__(16) float sredA[G_ROWS * SRED_LD];  //  5120 B
    __shared__ __align__(16) float sredB[G_ROWS * SRED_LD];  //  5120 B
    __shared__ __align__(16) float parr[G_ROWS * 4];         //  1024 B -> total 32768 B

    const int tid = threadIdx.x;
    const int ig = tid % G_IG;
    const int rg = tid / G_IG;
    const size_t rowBase = (size_t)blockIdx.x * G_ROWS;

    const float* Mc0 = ws + MC_OFF + 0 * MC_SIZE;
    const float* Mc1 = ws + MC_OFF + 1 * MC_SIZE;
    const float* Mc2 = ws + MC_OFF + 2 * MC_SIZE;
    const float* aug0 = ws + AUG_OFF + 0 * AUG_SIZE;
    const float* aug1 = ws + AUG_OFF + 1 * AUG_SIZE;
    const float* aug2 = ws + AUG_OFF + 2 * AUG_SIZE;

    const float4* gl = reinterpret_cast<const float4*>(xl_g + rowBase * D);
    const float4* gr = reinterpret_cast<const float4*>(xr_g + rowBase * D);
    const float4* gs = reinterpret_cast<const float4*>(xs_g + rowBase * D);

    float s0r = 0.f, s1r, s2r;   // meaningful on tid < 64 only

    // ---- stage LEFT tile ----
#pragma unroll
    for (int it = 0; it < 4; it++) {
        int u = tid + it * G_TPB;          // < 1280
        int r = u / 20, c = u % 20;
        *reinterpret_cast<float4*>(&X[r * XLD + c * 4]) = gl[u];
    }
    __syncthreads();

    // ---- pass 0: M_sl x left, dot = sub ----
    gemm_pass(Mc0, aug0, X, gs, ig, rg, sredA);
    __syncthreads();

    // ---- reduce s0 (wave 0) || stage RIGHT tile (all threads) ----
    if (tid < G_ROWS) {
        float a = aug0[D];                 // M_sl[80,80], uniform scalar
#pragma unroll
        for (int c = 0; c < SRED_LD; c++) a += sredA[tid * SRED_LD + c];
        s0r = a;
    }
#pragma unroll
    for (int it = 0; it < 4; it++) {
        int u = tid + it * G_TPB;
        int r = u / 20, c = u % 20;
        *reinterpret_cast<float4*>(&X[r * XLD + c * 4]) = gr[u];
    }
    __syncthreads();

    // ---- passes 1 & 2 back-to-back (both k-side = right; disjoint sred) ----
    gemm_pass(Mc1, aug1, X, gs, ig, rg, sredA);   // dot = sub
    gemm_pass(Mc2, aug2, X, gl, ig, rg, sredB);   // dot = left
    __syncthreads();

    // ---- reduce s1,s2 + softmax (wave 0) ----
    if (tid < G_ROWS) {
        float a = aug1[D];
        float b = aug2[D];
#pragma unroll
        for (int c = 0; c < SRED_LD; c++) {
            a += sredA[tid * SRED_LD + c];
            b += sredB[tid * SRED_LD + c];
        }
        s1r = a; s2r = b;
        float m = fmaxf(s0r, fmaxf(s1r, s2r));
        float e0 = __expf(s0r - m), e1 = __expf(s1r - m), e2 = __expf(s2r - m);
        float inv = 1.0f / (e0 + e1 + e2);
        parr[tid * 4 + 0] = e0 * inv;   // weight for left
        parr[tid * 4 + 1] = e1 * inv;   // weight for right
        parr[tid * 4 + 2] = e2 * inv;   // weight for sub
    }
    __syncthreads();

    // ---- combine + store (right from LDS X; left/sub from global L2-hot) ----
    {
        float4* go = reinterpret_cast<float4*>(out + rowBase * D);
#pragma unroll
        for (int it = 0; it < 4; it++) {
            int u = tid + it * G_TPB;
            int r = u / 20, c = u % 20;
            float p0 = parr[r * 4 + 0], p1 = parr[r * 4 + 1], p2 = parr[r * 4 + 2];
            float4 L = gl[u];
            float4 R = *reinterpret_cast<const float4*>(&X[r * XLD + c * 4]);
            float4 S = gs[u];
            float4 o;
            o.x = p0 * L.x + p1 * R.x + p2 * S.x;
            o.y = p0 * L.y + p1 * R.y + p2 * S.y;
            o.z = p0 * L.z + p1 * R.z + p2 * S.z;
            o.w = p0 * L.w + p1 * R.w + p2 * S.w;
            go[u] = o;
        }
    }
}

// ---------------------------------------------------------------------------
extern "C" void kernel_launch(void* const* d_in, const int* in_sizes, int n_in,
                              void* d_out, int out_size, void* d_ws, size_t ws_size,
                              hipStream_t stream) {
    const float* xs = (const float*)d_in[0];
    const float* xl = (const float*)d_in[1];
    const float* xr = (const float*)d_in[2];
    const float* Wsub = (const float*)d_in[3];
    const float* bsub = (const float*)d_in[4];
    const float* gsub = (const float*)d_in[5];
    const float* besub = (const float*)d_in[6];
    const float* Wleft = (const float*)d_in[7];
    const float* bleft = (const float*)d_in[8];
    const float* gleft = (const float*)d_in[9];
    const float* beleft = (const float*)d_in[10];
    const float* Wright = (const float*)d_in[11];
    const float* bright = (const float*)d_in[12];
    const float* gright = (const float*)d_in[13];
    const float* beright = (const float*)d_in[14];
    float* ws = (float*)d_ws;
    float* out = (float*)d_out;

    hipMemsetAsync(ws + S_OFF, 0, 3 * S_SIZE * sizeof(float), stream);

    k1_moments<<<dim3(K1_BLOCKS, 3), 256, 0, stream>>>(xs, xl, xr, ws);
    k2_T<<<(3 * DOUT * DA + 255) / 256, 256, 0, stream>>>(
        Wsub, bsub, Wleft, bleft, Wright, bright, ws);
    k2_scale<<<(3 * DOUT + 255) / 256, 256, 0, stream>>>(
        Wsub, bsub, gsub, besub, Wleft, bleft, gleft, beleft,
        Wright, bright, gright, beright, ws);
    k2_M<<<(3 * DA * DA + 255) / 256, 256, 0, stream>>>(ws);
    k3_main<<<N_ROWS / G_ROWS, G_TPB, 0, stream>>>(xs, xl, xr, ws, out);
}